// Round 6
// baseline (22631.189 us; speedup 1.0000x reference)
//
#include <hip/hip_runtime.h>
#include <math.h>

#define NBATCH 128
#define NTIME  256
#define NCH    512
#define NH     512
#define NSTEPS 32
#define NOUT   96
#define MTOT   32768
#define GRID_P 256

typedef __attribute__((ext_vector_type(8))) short short8v;
typedef __attribute__((ext_vector_type(4))) float f32x4;

__device__ __forceinline__ float fast_tanh(float x) {
    x = fminf(fmaxf(x, -30.f), 30.f);
    float u = __expf(2.f * x);
    return (u - 1.f) / (u + 1.f);
}
__device__ __forceinline__ float fast_sigmoid(float x) {
    x = fminf(fmaxf(x, -30.f), 30.f);
    return 1.f / (1.f + __expf(-x));
}
__device__ __forceinline__ float wave_reduce_sum(float s) {
    #pragma unroll
    for (int off = 32; off; off >>= 1) s += __shfl_xor(s, off, 64);
    return s;
}
__device__ __forceinline__ float wave_reduce_max(float s) {
    #pragma unroll
    for (int off = 32; off; off >>= 1) s = fmaxf(s, __shfl_xor(s, off, 64));
    return s;
}
__device__ __forceinline__ unsigned short f2bf(float f) {
    unsigned u = __builtin_bit_cast(unsigned, f);
    return (unsigned short)((u + 0x7FFFu + ((u >> 16) & 1u)) >> 16);
}
__device__ __forceinline__ float bflo(unsigned u) {
    return __builtin_bit_cast(float, u << 16);
}
__device__ __forceinline__ float bfhi(unsigned u) {
    return __builtin_bit_cast(float, u & 0xFFFF0000u);
}

// Device-wide barrier: monotonic counter, agent-scope atomics + fences.
// All 256 blocks are co-resident (96KB LDS -> 1 block/CU, grid == #CU).
__device__ __forceinline__ void gbar(int* cnt, int bar) {
    __threadfence();                 // release: drain writes, wbl2
    __syncthreads();
    if (threadIdx.x == 0) {
        __hip_atomic_fetch_add(cnt, 1, __ATOMIC_ACQ_REL, __HIP_MEMORY_SCOPE_AGENT);
        while (__hip_atomic_load(cnt, __ATOMIC_ACQUIRE, __HIP_MEMORY_SCOPE_AGENT)
               < bar * GRID_P)
            __builtin_amdgcn_s_sleep(2);
    }
    __syncthreads();
    __threadfence();                 // acquire: invalidate stale L1/L2
}

// ---------------------------------------------------------------------------
// Wi2h fp32 [512][512] -> bf16 same layout
__global__ __launch_bounds__(256) void k_w2bf(const float* __restrict__ W,
                                              unsigned short* __restrict__ Wb) {
    #pragma unroll
    for (int r = 0; r < 4; ++r) {
        int idx = (blockIdx.x * 256 + threadIdx.x) + r * 16384;
        float4 v = *(const float4*)(W + (size_t)idx * 4);
        ushort4 o;
        o.x = f2bf(v.x); o.y = f2bf(v.y); o.z = f2bf(v.z); o.w = f2bf(v.w);
        *(ushort4*)(Wb + (size_t)idx * 4) = o;
    }
}

// ---------------------------------------------------------------------------
// feats fp32 [k=512][m=32768] -> featsT bf16 [m][k]
__global__ __launch_bounds__(256) void k_feats2bf(const float* __restrict__ feats,
                                                  unsigned short* __restrict__ Fb) {
    __shared__ float tl[64][65];
    const int m0 = (blockIdx.x & 511) * 64;
    const int k0 = (blockIdx.x >> 9) * 64;
    const int tid = threadIdx.x;
    #pragma unroll
    for (int p = 0; p < 4; ++p) {
        int fid = tid + p * 256;
        int row = fid >> 4, c4 = fid & 15;
        float4 v = *(const float4*)(feats + (size_t)(k0 + row) * MTOT + m0 + c4 * 4);
        tl[row][c4 * 4 + 0] = v.x; tl[row][c4 * 4 + 1] = v.y;
        tl[row][c4 * 4 + 2] = v.z; tl[row][c4 * 4 + 3] = v.w;
    }
    __syncthreads();
    #pragma unroll
    for (int p = 0; p < 4; ++p) {
        int cid = tid + p * 256;
        int mm = cid >> 4, ch = cid & 15;
        ushort4 o;
        o.x = f2bf(tl[ch * 4 + 0][mm]);
        o.y = f2bf(tl[ch * 4 + 1][mm]);
        o.z = f2bf(tl[ch * 4 + 2][mm]);
        o.w = f2bf(tl[ch * 4 + 3][mm]);
        *(ushort4*)(Fb + (size_t)(m0 + mm) * 512 + k0 + ch * 4) = o;
    }
}

// ---------------------------------------------------------------------------
// feats fp32 [c][b][t] -> bf16 same layout
__global__ __launch_bounds__(1024) void k_fcopy(const float* __restrict__ f,
                                                unsigned short* __restrict__ o) {
    int gid = blockIdx.x * 1024 + threadIdx.x;
    float4 v = *(const float4*)(f + (size_t)gid * 4);
    ushort4 s;
    s.x = f2bf(v.x); s.y = f2bf(v.y); s.z = f2bf(v.z); s.w = f2bf(v.w);
    *(ushort4*)(o + (size_t)gid * 4) = s;
}

// ---------------------------------------------------------------------------
// MFMA GEMM: fp[m][h] = sum_k featsT[m][k] * Wi2h[h][k]  (bf16 in, bf16 out)
__global__ __launch_bounds__(256) void k_fp_mfma(const unsigned short* __restrict__ Wb,
                                                 const unsigned short* __restrict__ Fb,
                                                 unsigned short* __restrict__ fp_bf) {
    __shared__ char SB[49152];
    unsigned short* As = (unsigned short*)SB;            // [128 h][64 k]
    unsigned short* Bs = (unsigned short*)(SB + 16384);  // [256 m][64 k]
    float* tl = (float*)SB;                              // [256 m][33]
    const int m0 = (blockIdx.x & 127) * 256;
    const int h0 = (blockIdx.x >> 7) * 128;
    const int tid = threadIdx.x;
    const int lane = tid & 63, wid = tid >> 6;
    const int wh = wid & 1, wm = wid >> 1;
    f32x4 acc[4][8];
    #pragma unroll
    for (int i = 0; i < 4; ++i)
        #pragma unroll
        for (int j = 0; j < 8; ++j) acc[i][j] = (f32x4)0.f;

    for (int k0 = 0; k0 < 512; k0 += 64) {
        #pragma unroll
        for (int i = 0; i < 4; ++i) {
            int cid = tid + i * 256;
            int row = cid >> 3, ch = cid & 7;
            uint4 v = *(const uint4*)(Wb + (size_t)(h0 + row) * 512 + k0 + ch * 8);
            *(uint4*)(As + row * 64 + ((ch ^ (row & 7)) << 3)) = v;
        }
        #pragma unroll
        for (int i = 0; i < 8; ++i) {
            int cid = tid + i * 256;
            int row = cid >> 3, ch = cid & 7;
            uint4 v = *(const uint4*)(Fb + (size_t)(m0 + row) * 512 + k0 + ch * 8);
            *(uint4*)(Bs + row * 64 + ((ch ^ (row & 7)) << 3)) = v;
        }
        __syncthreads();
        #pragma unroll
        for (int ks = 0; ks < 2; ++ks) {
            short8v a[4], b[8];
            #pragma unroll
            for (int hf = 0; hf < 4; ++hf) {
                int row = wh * 64 + hf * 16 + (lane & 15);
                int ch = ks * 4 + (lane >> 4);
                a[hf] = *(const short8v*)(As + row * 64 + ((ch ^ (row & 7)) << 3));
            }
            #pragma unroll
            for (int mf = 0; mf < 8; ++mf) {
                int row = wm * 128 + mf * 16 + (lane & 15);
                int ch = ks * 4 + (lane >> 4);
                b[mf] = *(const short8v*)(Bs + row * 64 + ((ch ^ (row & 7)) << 3));
            }
            #pragma unroll
            for (int hf = 0; hf < 4; ++hf)
                #pragma unroll
                for (int mf = 0; mf < 8; ++mf)
                    acc[hf][mf] = __builtin_amdgcn_mfma_f32_16x16x32_bf16(
                        a[hf], b[mf], acc[hf][mf], 0, 0, 0);
        }
        __syncthreads();
    }
    #pragma unroll
    for (int hf = 0; hf < 4; ++hf) {
        #pragma unroll
        for (int mf = 0; mf < 8; ++mf) {
            int ml = wm * 128 + mf * 16 + (lane & 15);
            int col = wh * 16 + (lane >> 4) * 4;
            tl[ml * 33 + col + 0] = acc[hf][mf][0];
            tl[ml * 33 + col + 1] = acc[hf][mf][1];
            tl[ml * 33 + col + 2] = acc[hf][mf][2];
            tl[ml * 33 + col + 3] = acc[hf][mf][3];
        }
        __syncthreads();
        #pragma unroll
        for (int mi = 0; mi < 8; ++mi) {
            int ml = (tid >> 3) + mi * 32;
            int hl4 = (tid & 7) * 4;
            float v0 = tl[ml * 33 + hl4 + 0];
            float v1 = tl[ml * 33 + hl4 + 1];
            float v2 = tl[ml * 33 + hl4 + 2];
            float v3 = tl[ml * 33 + hl4 + 3];
            int hg = h0 + ((hl4 < 16) ? (hf * 16 + hl4) : (64 + hf * 16 + hl4 - 16));
            ushort4 o;
            o.x = f2bf(v0); o.y = f2bf(v1); o.z = f2bf(v2); o.w = f2bf(v3);
            *(ushort4*)(fp_bf + (size_t)(m0 + ml) * 512 + hg) = o;
        }
        __syncthreads();
    }
}

// ---------------------------------------------------------------------------
// Transpose Wh2h[512][512] -> WT[k][j]
__global__ __launch_bounds__(256) void k_wt(const float* __restrict__ W,
                                            float* __restrict__ WT) {
    __shared__ float tl[32][33];
    const int bi = blockIdx.x & 15, bj = blockIdx.x >> 4;
    const int tx = threadIdx.x & 31, ty8 = threadIdx.x >> 5;
    #pragma unroll
    for (int i = 0; i < 4; ++i) {
        int r = ty8 * 4 + i;
        tl[r][tx] = W[(size_t)(bj * 32 + r) * NH + bi * 32 + tx];
    }
    __syncthreads();
    #pragma unroll
    for (int i = 0; i < 4; ++i) {
        int c = ty8 * 4 + i;
        WT[(size_t)(bi * 32 + c) * NH + bj * 32 + tx] = tl[tx][c];
    }
}

// ---------------------------------------------------------------------------
// Persistent loop kernel: 32 steps x {e | sm+ctx | gates | comb+hp},
// separated by device-wide barriers. 256 blocks x 1024 threads, 96KB LDS.
__global__ __launch_bounds__(1024) void k_loop(
    const unsigned short* __restrict__ fp_bf,
    const unsigned short* __restrict__ featsb,
    const float* __restrict__ wscore,
    const float* __restrict__ Wih,
    const float* __restrict__ Whh,
    const float* __restrict__ bih,
    const float* __restrict__ bhh,
    const float* __restrict__ WT,
    const float* __restrict__ bh2h,
    float* __restrict__ hid,
    float* __restrict__ hpctx,
    float* __restrict__ e,
    float* __restrict__ g2,
    int* cnt)
{
    __shared__ float S[24576];          // 96 KB, re-carved per phase
    const int blk = blockIdx.x;
    const int tid = threadIdx.x;
    const int lane = tid & 63, w = tid >> 6;
    int bar = 0;

    // P0: hp = bh2h broadcast; h0 = 0
    {
        int i = blk * 1024 + tid;
        if (i < 65536) { hpctx[i] = bh2h[i & 511]; hid[i] = 0.f; }
    }
    gbar(cnt, ++bar);

    for (int s = 0; s < NSTEPS; ++s) {
        const float* h = hid + (size_t)s * 65536;
        float* hn      = hid + (size_t)(s + 1) * 65536;

        // ---- P1: e[b][t] = sum_h tanh(fp+hp)*w ----
        {
            const int b = blk >> 1;
            const int t0 = (blk & 1) * 128;
            float4 h0 = *(const float4*)(hpctx + (size_t)b * NH + lane * 8);
            float4 h1 = *(const float4*)(hpctx + (size_t)b * NH + lane * 8 + 4);
            float4 w0 = *(const float4*)(wscore + lane * 8);
            float4 w1 = *(const float4*)(wscore + lane * 8 + 4);
            #pragma unroll 2
            for (int it = 0; it < 8; ++it) {
                int t = t0 + w * 8 + it;
                uint4 v = *(const uint4*)(fp_bf + (size_t)(b * NTIME + t) * NH + lane * 8);
                float sv =
                    fast_tanh(bflo(v.x) + h0.x) * w0.x + fast_tanh(bfhi(v.x) + h0.y) * w0.y +
                    fast_tanh(bflo(v.y) + h0.z) * w0.z + fast_tanh(bfhi(v.y) + h0.w) * w0.w +
                    fast_tanh(bflo(v.z) + h1.x) * w1.x + fast_tanh(bfhi(v.z) + h1.y) * w1.y +
                    fast_tanh(bflo(v.w) + h1.z) * w1.z + fast_tanh(bfhi(v.w) + h1.w) * w1.w;
                sv = wave_reduce_sum(sv);
                if (lane == 0) e[b * NTIME + t] = sv;
            }
        }
        gbar(cnt, ++bar);

        // ---- P2: softmax(e[b]) + ctx[b][c] (ctx overwrites hp) ----
        {
            float* als = S;              // 256
            float* red = S + 256;        // 16
            const int b = blk >> 1;
            const int c0 = (blk & 1) * 256;
            float v = (tid < 256) ? e[b * NTIME + tid] : -3.4e38f;
            float m = wave_reduce_max(v);
            if (lane == 0) red[w] = m;
            __syncthreads();
            m = red[0];
            #pragma unroll
            for (int i = 1; i < 16; ++i) m = fmaxf(m, red[i]);
            float ex = (tid < 256) ? __expf(v - m) : 0.f;
            float sm = wave_reduce_sum(ex);
            __syncthreads();
            if (lane == 0) red[w] = sm;
            __syncthreads();
            sm = 0.f;
            #pragma unroll
            for (int i = 0; i < 16; ++i) sm += red[i];
            if (tid < 256) als[tid] = ex / sm;
            __syncthreads();
            float4 al = *(const float4*)&als[lane * 4];
            #pragma unroll 4
            for (int cc = 0; cc < 16; ++cc) {
                int c = c0 + w * 16 + cc;
                uint2 fv = *(const uint2*)(featsb + (size_t)(c * NBATCH + b) * NTIME + lane * 4);
                float sc = bflo(fv.x) * al.x + bfhi(fv.x) * al.y +
                           bflo(fv.y) * al.z + bfhi(fv.y) * al.w;
                sc = wave_reduce_sum(sc);
                if (lane == 0) hpctx[(size_t)b * NCH + c] = sc;
            }
        }
        gbar(cnt, ++bar);

        // ---- P3: gates g2[g][j][b] (192 active blocks) ----
        if (blk < 192) {
            float* A_ldsT = S;           // 16384
            float* scr    = S + 16384;   // 8192
            const int g   = blk >> 5;
            const int j0  = (blk & 31) * 16;
            const float* A = (g < 3) ? hpctx : h;
            const float* W = (g < 3) ? Wih : Whh;
            const int m2  = tid & 63;
            const int q   = __builtin_amdgcn_readfirstlane(tid >> 6);
            const int nq  = q & 3, kq = q >> 2;
            const float* Wr0 = W + (size_t)((g % 3) * 512 + j0 + nq * 4 + 0) * NH;
            const float* Wr1 = W + (size_t)((g % 3) * 512 + j0 + nq * 4 + 1) * NH;
            const float* Wr2 = W + (size_t)((g % 3) * 512 + j0 + nq * 4 + 2) * NH;
            const float* Wr3 = W + (size_t)((g % 3) * 512 + j0 + nq * 4 + 3) * NH;
            float acc[2][4] = {};
            for (int kt = 0; kt < 4; ++kt) {
                {
                    int m = tid & 127, kc = tid >> 7;
                    #pragma unroll
                    for (int q4 = 0; q4 < 4; ++q4) {
                        int kk = kc * 16 + q4 * 4;
                        float4 vv = *(const float4*)(A + (size_t)m * NH + kt * 128 + kk);
                        A_ldsT[(kk + 0) * 128 + m] = vv.x;
                        A_ldsT[(kk + 1) * 128 + m] = vv.y;
                        A_ldsT[(kk + 2) * 128 + m] = vv.z;
                        A_ldsT[(kk + 3) * 128 + m] = vv.w;
                    }
                }
                __syncthreads();
                const int kbase = kt * 128;
                #pragma unroll 8
                for (int kk = kq * 32; kk < kq * 32 + 32; ++kk) {
                    float a0 = A_ldsT[kk * 128 + m2];
                    float a1 = A_ldsT[kk * 128 + m2 + 64];
                    float w0 = Wr0[kbase + kk], w1 = Wr1[kbase + kk];
                    float w2 = Wr2[kbase + kk], w3 = Wr3[kbase + kk];
                    acc[0][0] += a0 * w0; acc[0][1] += a0 * w1;
                    acc[0][2] += a0 * w2; acc[0][3] += a0 * w3;
                    acc[1][0] += a1 * w0; acc[1][1] += a1 * w1;
                    acc[1][2] += a1 * w2; acc[1][3] += a1 * w3;
                }
                __syncthreads();
            }
            #pragma unroll
            for (int hi = 0; hi < 2; ++hi)
                #pragma unroll
                for (int r = 0; r < 4; ++r)
                    scr[(kq * 16 + nq * 4 + r) * 128 + m2 + 64 * hi] = acc[hi][r];
            __syncthreads();
            #pragma unroll
            for (int rep = 0; rep < 2; ++rep) {
                int oid = tid + rep * 1024;
                int m = oid & 127, nl = oid >> 7;
                float vv = scr[(0 * 16 + nl) * 128 + m] + scr[(1 * 16 + nl) * 128 + m] +
                           scr[(2 * 16 + nl) * 128 + m] + scr[(3 * 16 + nl) * 128 + m];
                g2[(size_t)(g * 512 + j0 + nl) * NBATCH + m] = vv;
            }
        }
        gbar(cnt, ++bar);

        // ---- P4: GRU combine -> h_new; hp_next = h_new @ WT + bh2h ----
        {
            float* h_s  = S;             // 2048
            float* scr2 = S + 2048;      // 4096
            const int b0 = (blk >> 3) * 4;
            const int jbase = (blk & 7) * 64;
            #pragma unroll
            for (int rep = 0; rep < 2; ++rep) {
                int idx = tid + rep * 1024;
                int bi = idx & 3, kk = idx >> 2;
                int b = b0 + bi;
                float ir  = g2[(size_t)(0 * 512 + kk) * NBATCH + b] + bih[kk];
                float iz  = g2[(size_t)(1 * 512 + kk) * NBATCH + b] + bih[512 + kk];
                float in_ = g2[(size_t)(2 * 512 + kk) * NBATCH + b] + bih[1024 + kk];
                float hr  = g2[(size_t)(3 * 512 + kk) * NBATCH + b] + bhh[kk];
                float hz  = g2[(size_t)(4 * 512 + kk) * NBATCH + b] + bhh[512 + kk];
                float hnn = g2[(size_t)(5 * 512 + kk) * NBATCH + b] + bhh[1024 + kk];
                float r = fast_sigmoid(ir + hr);
                float z = fast_sigmoid(iz + hz);
                float ng = fast_tanh(in_ + r * hnn);
                float hv = h[(size_t)b * NH + kk];
                float hnew = (1.f - z) * ng + z * hv;
                h_s[bi * 512 + kk] = hnew;
                if ((blk & 7) == 0) hn[(size_t)b * NH + kk] = hnew;
            }
            __syncthreads();
            {
                const int jq = tid & 15, bi = (tid >> 4) & 3, kq = tid >> 6;
                const int j = jbase + jq * 4;
                float4 acc = make_float4(0.f, 0.f, 0.f, 0.f);
                #pragma unroll 8
                for (int kk = 0; kk < 32; ++kk) {
                    int k = kq * 32 + kk;
                    float4 wv = *(const float4*)(WT + (size_t)k * NH + j);
                    float hv = h_s[bi * 512 + k];
                    acc.x += hv * wv.x; acc.y += hv * wv.y;
                    acc.z += hv * wv.z; acc.w += hv * wv.w;
                }
                *(float4*)&scr2[((kq * 4 + bi) * 16 + jq) * 4] = acc;
            }
            __syncthreads();
            if (tid < 64) {
                const int bi = tid >> 4, jq = tid & 15;
                float4 sum = make_float4(0.f, 0.f, 0.f, 0.f);
                #pragma unroll
                for (int kq = 0; kq < 16; ++kq) {
                    float4 p = *(const float4*)&scr2[((kq * 4 + bi) * 16 + jq) * 4];
                    sum.x += p.x; sum.y += p.y; sum.z += p.z; sum.w += p.w;
                }
                int j = jbase + jq * 4;
                float4 bb = *(const float4*)(bh2h + j);
                sum.x += bb.x; sum.y += bb.y; sum.z += bb.z; sum.w += bb.w;
                *(float4*)(hpctx + (size_t)(b0 + bi) * NH + j) = sum;
            }
        }
        gbar(cnt, ++bar);
    }
}

// ---------------------------------------------------------------------------
__global__ __launch_bounds__(256) void k_gen(const float* __restrict__ hid,
                                             const float* __restrict__ Wgen,
                                             const float* __restrict__ bgen,
                                             float* __restrict__ out) {
    __shared__ float As[32][36];
    __shared__ float Bs[32][97];
    const int m0 = blockIdx.x * 32;
    const int tid = threadIdx.x;
    const int tx = tid & 31, ty = tid >> 5;
    float acc[4][3] = {};
    for (int k0 = 0; k0 < 512; k0 += 32) {
        {
            int mm = tid >> 3, kq = (tid & 7) << 2;
            int m = m0 + mm, s = m & 31, b = m >> 5;
            float4 v = *(const float4*)(hid + (size_t)(s + 1) * 65536 + b * 512 + k0 + kq);
            *(float4*)(&As[mm][kq]) = v;
        }
        #pragma unroll
        for (int i = 0; i < 3; ++i) {
            int f4 = tid + i * 256;
            int nn = f4 >> 3, kq = (f4 & 7) << 2;
            float4 v = *(const float4*)(Wgen + (size_t)nn * 512 + k0 + kq);
            Bs[kq + 0][nn] = v.x; Bs[kq + 1][nn] = v.y;
            Bs[kq + 2][nn] = v.z; Bs[kq + 3][nn] = v.w;
        }
        __syncthreads();
        #pragma unroll
        for (int kk = 0; kk < 32; ++kk) {
            float bv[3];
            #pragma unroll
            for (int j = 0; j < 3; ++j) bv[j] = Bs[kk][tx * 3 + j];
            #pragma unroll
            for (int i = 0; i < 4; ++i) {
                float a = As[ty * 4 + i][kk];
                #pragma unroll
                for (int j = 0; j < 3; ++j) acc[i][j] += a * bv[j];
            }
        }
        __syncthreads();
    }
    #pragma unroll
    for (int i = 0; i < 4; ++i)
        #pragma unroll
        for (int j = 0; j < 3; ++j)
            out[(size_t)(m0 + ty * 4 + i) * NOUT + tx * 3 + j] = acc[i][j] + bgen[tx * 3 + j];
}

// ---------------------------------------------------------------------------
extern "C" void kernel_launch(void* const* d_in, const int* in_sizes, int n_in,
                              void* d_out, int out_size, void* d_ws, size_t ws_size,
                              hipStream_t stream) {
    const float* feats  = (const float*)d_in[0];
    const float* Wi2h   = (const float*)d_in[2];
    const float* Wh2h   = (const float*)d_in[3];
    const float* bh2h   = (const float*)d_in[4];
    const float* Wscore = (const float*)d_in[5];
    const float* Wih    = (const float*)d_in[6];
    const float* Whh    = (const float*)d_in[7];
    const float* bih    = (const float*)d_in[8];
    const float* bhh    = (const float*)d_in[9];
    const float* Wgen   = (const float*)d_in[10];
    const float* bgen   = (const float*)d_in[11];
    float* out = (float*)d_out;

    // ws (float slots): fp_bf(8388608) hid(2162688) WT(262144) hpctx(65536)
    //                   Wb(131072) Fb/featsb(8388608) cnt(1)
    float* ws  = (float*)d_ws;
    unsigned short* fp_bf = (unsigned short*)ws;
    float* hid   = ws + 8388608;
    float* WT    = hid + 2162688;
    float* hpctx = WT + 262144;
    unsigned short* Wb     = (unsigned short*)(hpctx + 65536);
    unsigned short* Fb     = (unsigned short*)(hpctx + 65536 + 131072);
    unsigned short* featsb = Fb;    // reuses Fb space after k_fp_mfma
    int* cnt = (int*)(hpctx + 65536 + 131072 + 8388608);

    float* e  = out;                // aliases g2 head; disjoint lifetimes
    float* g2 = out;                // 6*512*128 = 393216 = out_size

    hipMemsetAsync(cnt, 0, sizeof(int), stream);
    k_wt<<<256, 256, 0, stream>>>(Wh2h, WT);
    k_w2bf<<<64, 256, 0, stream>>>(Wi2h, Wb);
    k_feats2bf<<<4096, 256, 0, stream>>>(feats, Fb);
    k_fp_mfma<<<512, 256, 0, stream>>>(Wb, Fb, fp_bf);
    k_fcopy<<<4096, 1024, 0, stream>>>(feats, featsb);

    k_loop<<<GRID_P, 1024, 0, stream>>>(fp_bf, featsb, Wscore, Wih, Whh,
                                        bih, bhh, WT, bh2h, hid, hpctx,
                                        e, g2, cnt);

    k_gen<<<128, 256, 0, stream>>>(hid, Wgen, bgen, out);
}

// Round 7
// 3877.082 us; speedup vs baseline: 5.8372x; 5.8372x over previous
//
#include <hip/hip_runtime.h>
#include <math.h>

#define NBATCH 128
#define NTIME  256
#define NCH    512
#define NH     512
#define NSTEPS 32
#define NOUT   96
#define MTOT   32768

typedef __attribute__((ext_vector_type(8))) short short8v;
typedef __attribute__((ext_vector_type(4))) float f32x4;

__device__ __forceinline__ float fast_tanh(float x) {
    x = fminf(fmaxf(x, -30.f), 30.f);
    float u = __expf(2.f * x);
    return (u - 1.f) / (u + 1.f);
}
__device__ __forceinline__ float fast_sigmoid(float x) {
    x = fminf(fmaxf(x, -30.f), 30.f);
    return 1.f / (1.f + __expf(-x));
}
__device__ __forceinline__ float wave_reduce_sum(float s) {
    #pragma unroll
    for (int off = 32; off; off >>= 1) s += __shfl_xor(s, off, 64);
    return s;
}
__device__ __forceinline__ float wave_reduce_max(float s) {
    #pragma unroll
    for (int off = 32; off; off >>= 1) s = fmaxf(s, __shfl_xor(s, off, 64));
    return s;
}
__device__ __forceinline__ unsigned short f2bf(float f) {
    unsigned u = __builtin_bit_cast(unsigned, f);
    return (unsigned short)((u + 0x7FFFu + ((u >> 16) & 1u)) >> 16);
}
__device__ __forceinline__ float bflo(unsigned u) {
    return __builtin_bit_cast(float, u << 16);
}
__device__ __forceinline__ float bfhi(unsigned u) {
    return __builtin_bit_cast(float, u & 0xFFFF0000u);
}

// ---------------------------------------------------------------------------
// Wi2h fp32 [512][512] -> bf16 same layout
__global__ __launch_bounds__(256) void k_w2bf(const float* __restrict__ W,
                                              unsigned short* __restrict__ Wb) {
    #pragma unroll
    for (int r = 0; r < 4; ++r) {
        int idx = (blockIdx.x * 256 + threadIdx.x) + r * 16384;
        float4 v = *(const float4*)(W + (size_t)idx * 4);
        ushort4 o;
        o.x = f2bf(v.x); o.y = f2bf(v.y); o.z = f2bf(v.z); o.w = f2bf(v.w);
        *(ushort4*)(Wb + (size_t)idx * 4) = o;
    }
}

// ---------------------------------------------------------------------------
// feats fp32 [k=512][m=32768] -> featsT bf16 [m][k]
__global__ __launch_bounds__(256) void k_feats2bf(const float* __restrict__ feats,
                                                  unsigned short* __restrict__ Fb) {
    __shared__ float tl[64][65];
    const int m0 = (blockIdx.x & 511) * 64;
    const int k0 = (blockIdx.x >> 9) * 64;
    const int tid = threadIdx.x;
    #pragma unroll
    for (int p = 0; p < 4; ++p) {
        int fid = tid + p * 256;
        int row = fid >> 4, c4 = fid & 15;
        float4 v = *(const float4*)(feats + (size_t)(k0 + row) * MTOT + m0 + c4 * 4);
        tl[row][c4 * 4 + 0] = v.x; tl[row][c4 * 4 + 1] = v.y;
        tl[row][c4 * 4 + 2] = v.z; tl[row][c4 * 4 + 3] = v.w;
    }
    __syncthreads();
    #pragma unroll
    for (int p = 0; p < 4; ++p) {
        int cid = tid + p * 256;
        int mm = cid >> 4, ch = cid & 15;
        ushort4 o;
        o.x = f2bf(tl[ch * 4 + 0][mm]);
        o.y = f2bf(tl[ch * 4 + 1][mm]);
        o.z = f2bf(tl[ch * 4 + 2][mm]);
        o.w = f2bf(tl[ch * 4 + 3][mm]);
        *(ushort4*)(Fb + (size_t)(m0 + mm) * 512 + k0 + ch * 4) = o;
    }
}

// ---------------------------------------------------------------------------
// feats fp32 [c][b][t] -> bf16 same layout
__global__ __launch_bounds__(1024) void k_fcopy(const float* __restrict__ f,
                                                unsigned short* __restrict__ o) {
    int gid = blockIdx.x * 1024 + threadIdx.x;
    float4 v = *(const float4*)(f + (size_t)gid * 4);
    ushort4 s;
    s.x = f2bf(v.x); s.y = f2bf(v.y); s.z = f2bf(v.z); s.w = f2bf(v.w);
    *(ushort4*)(o + (size_t)gid * 4) = s;
}

// ---------------------------------------------------------------------------
// MFMA GEMM: fp[m][h] = sum_k featsT[m][k] * Wi2h[h][k]  (bf16 in, bf16 out)
__global__ __launch_bounds__(256) void k_fp_mfma(const unsigned short* __restrict__ Wb,
                                                 const unsigned short* __restrict__ Fb,
                                                 unsigned short* __restrict__ fp_bf) {
    __shared__ char SB[49152];
    unsigned short* As = (unsigned short*)SB;            // [128 h][64 k]
    unsigned short* Bs = (unsigned short*)(SB + 16384);  // [256 m][64 k]
    float* tl = (float*)SB;                              // [256 m][33]
    const int m0 = (blockIdx.x & 127) * 256;
    const int h0 = (blockIdx.x >> 7) * 128;
    const int tid = threadIdx.x;
    const int lane = tid & 63, wid = tid >> 6;
    const int wh = wid & 1, wm = wid >> 1;
    f32x4 acc[4][8];
    #pragma unroll
    for (int i = 0; i < 4; ++i)
        #pragma unroll
        for (int j = 0; j < 8; ++j) acc[i][j] = (f32x4)0.f;

    for (int k0 = 0; k0 < 512; k0 += 64) {
        #pragma unroll
        for (int i = 0; i < 4; ++i) {
            int cid = tid + i * 256;
            int row = cid >> 3, ch = cid & 7;
            uint4 v = *(const uint4*)(Wb + (size_t)(h0 + row) * 512 + k0 + ch * 8);
            *(uint4*)(As + row * 64 + ((ch ^ (row & 7)) << 3)) = v;
        }
        #pragma unroll
        for (int i = 0; i < 8; ++i) {
            int cid = tid + i * 256;
            int row = cid >> 3, ch = cid & 7;
            uint4 v = *(const uint4*)(Fb + (size_t)(m0 + row) * 512 + k0 + ch * 8);
            *(uint4*)(Bs + row * 64 + ((ch ^ (row & 7)) << 3)) = v;
        }
        __syncthreads();
        #pragma unroll
        for (int ks = 0; ks < 2; ++ks) {
            short8v a[4], b[8];
            #pragma unroll
            for (int hf = 0; hf < 4; ++hf) {
                int row = wh * 64 + hf * 16 + (lane & 15);
                int ch = ks * 4 + (lane >> 4);
                a[hf] = *(const short8v*)(As + row * 64 + ((ch ^ (row & 7)) << 3));
            }
            #pragma unroll
            for (int mf = 0; mf < 8; ++mf) {
                int row = wm * 128 + mf * 16 + (lane & 15);
                int ch = ks * 4 + (lane >> 4);
                b[mf] = *(const short8v*)(Bs + row * 64 + ((ch ^ (row & 7)) << 3));
            }
            #pragma unroll
            for (int hf = 0; hf < 4; ++hf)
                #pragma unroll
                for (int mf = 0; mf < 8; ++mf)
                    acc[hf][mf] = __builtin_amdgcn_mfma_f32_16x16x32_bf16(
                        a[hf], b[mf], acc[hf][mf], 0, 0, 0);
        }
        __syncthreads();
    }
    #pragma unroll
    for (int hf = 0; hf < 4; ++hf) {
        #pragma unroll
        for (int mf = 0; mf < 8; ++mf) {
            int ml = wm * 128 + mf * 16 + (lane & 15);
            int col = wh * 16 + (lane >> 4) * 4;
            tl[ml * 33 + col + 0] = acc[hf][mf][0];
            tl[ml * 33 + col + 1] = acc[hf][mf][1];
            tl[ml * 33 + col + 2] = acc[hf][mf][2];
            tl[ml * 33 + col + 3] = acc[hf][mf][3];
        }
        __syncthreads();
        #pragma unroll
        for (int mi = 0; mi < 8; ++mi) {
            int ml = (tid >> 3) + mi * 32;
            int hl4 = (tid & 7) * 4;
            float v0 = tl[ml * 33 + hl4 + 0];
            float v1 = tl[ml * 33 + hl4 + 1];
            float v2 = tl[ml * 33 + hl4 + 2];
            float v3 = tl[ml * 33 + hl4 + 3];
            int hg = h0 + ((hl4 < 16) ? (hf * 16 + hl4) : (64 + hf * 16 + hl4 - 16));
            ushort4 o;
            o.x = f2bf(v0); o.y = f2bf(v1); o.z = f2bf(v2); o.w = f2bf(v3);
            *(ushort4*)(fp_bf + (size_t)(m0 + ml) * 512 + hg) = o;
        }
        __syncthreads();
    }
}

// ---------------------------------------------------------------------------
// K_A: fused per-batch attention step. 128 blocks x 1024 (16 waves).
// Phases: hp = h@Wh2h^T + bh2h (rows via L2 broadcast) -> e -> softmax -> ctx.
__global__ __launch_bounds__(1024) void k_att(
    const unsigned short* __restrict__ fp_bf,
    const unsigned short* __restrict__ featsb,
    const float* __restrict__ hcur,
    const float* __restrict__ Wh2h,
    const float* __restrict__ bh2h,
    const float* __restrict__ wscore,
    float* __restrict__ ctx)
{
    __shared__ float h_s[512];
    __shared__ float hp_s[512];
    __shared__ float e_s[256];
    __shared__ float red[16];
    const int b = blockIdx.x;
    const int tid = threadIdx.x;
    const int lane = tid & 63, w = tid >> 6;

    if (tid < 512) h_s[tid] = hcur[(size_t)b * NH + tid];
    __syncthreads();

    // A1: hp[j]; wave w covers j = w*32 .. +31
    {
        float4 ha = *(const float4*)&h_s[lane * 8];
        float4 hb = *(const float4*)&h_s[lane * 8 + 4];
        #pragma unroll 4
        for (int jj = 0; jj < 32; ++jj) {
            int j = w * 32 + jj;
            const float4* wr = (const float4*)(Wh2h + (size_t)j * NH + lane * 8);
            float4 w0 = wr[0], w1 = wr[1];
            float s = ha.x * w0.x + ha.y * w0.y + ha.z * w0.z + ha.w * w0.w +
                      hb.x * w1.x + hb.y * w1.y + hb.z * w1.z + hb.w * w1.w;
            s = wave_reduce_sum(s);
            if (lane == 0) hp_s[j] = s + bh2h[j];
        }
    }
    __syncthreads();

    // A2: e[t] = sum_h tanh(fp+hp)*wscore; wave w: t = w*16 .. +15
    {
        float4 hp0 = *(const float4*)&hp_s[lane * 8];
        float4 hp1 = *(const float4*)&hp_s[lane * 8 + 4];
        float4 w0 = *(const float4*)(wscore + lane * 8);
        float4 w1 = *(const float4*)(wscore + lane * 8 + 4);
        #pragma unroll 4
        for (int ti = 0; ti < 16; ++ti) {
            int t = w * 16 + ti;
            uint4 v = *(const uint4*)(fp_bf + (size_t)(b * NTIME + t) * NH + lane * 8);
            float sv =
                fast_tanh(bflo(v.x) + hp0.x) * w0.x + fast_tanh(bfhi(v.x) + hp0.y) * w0.y +
                fast_tanh(bflo(v.y) + hp0.z) * w0.z + fast_tanh(bfhi(v.y) + hp0.w) * w0.w +
                fast_tanh(bflo(v.z) + hp1.x) * w1.x + fast_tanh(bfhi(v.z) + hp1.y) * w1.y +
                fast_tanh(bflo(v.w) + hp1.z) * w1.z + fast_tanh(bfhi(v.w) + hp1.w) * w1.w;
            sv = wave_reduce_sum(sv);
            if (lane == 0) e_s[t] = sv;
        }
    }
    __syncthreads();

    // A3: softmax over e_s[0..255] -> alpha back into e_s
    {
        float v = (tid < 256) ? e_s[tid] : -3.4e38f;
        float m = wave_reduce_max(v);
        if (lane == 0) red[w] = m;
        __syncthreads();
        m = red[0];
        #pragma unroll
        for (int i = 1; i < 16; ++i) m = fmaxf(m, red[i]);
        float ex = (tid < 256) ? __expf(v - m) : 0.f;
        float sm = wave_reduce_sum(ex);
        __syncthreads();
        if (lane == 0) red[w] = sm;
        __syncthreads();
        sm = 0.f;
        #pragma unroll
        for (int i = 0; i < 16; ++i) sm += red[i];
        __syncthreads();
        if (tid < 256) e_s[tid] = ex / sm;
    }
    __syncthreads();

    // A4: ctx[c] = sum_t feats[c][b][t]*alpha[t]; wave w: c = w*32 .. +31
    {
        float4 al = *(const float4*)&e_s[lane * 4];
        #pragma unroll 4
        for (int cc = 0; cc < 32; ++cc) {
            int c = w * 32 + cc;
            uint2 fv = *(const uint2*)(featsb + (size_t)(c * NBATCH + b) * NTIME + lane * 4);
            float sc = bflo(fv.x) * al.x + bfhi(fv.x) * al.y +
                       bflo(fv.y) * al.z + bfhi(fv.y) * al.w;
            sc = wave_reduce_sum(sc);
            if (lane == 0) ctx[(size_t)b * NCH + c] = sc;
        }
    }
}

// ---------------------------------------------------------------------------
// K_B: fused 6-gate GEMM + GRU combine, j-sliced. 128 blocks x 1024.
// Block owns j in [4*blk, 4*blk+4): computes g[g][j][b] for all 6 g, all 128 b,
// then combines -> hnext[b][j]. A-panels (ctx,h) staged fp32 in LDS k-tiles;
// weights via wave-uniform s_loads (kq forced uniform).
__global__ __launch_bounds__(1024) void k_gru(
    const float* __restrict__ ctx,
    const float* __restrict__ hcur,
    const float* __restrict__ Wih,
    const float* __restrict__ Whh,
    const float* __restrict__ bih,
    const float* __restrict__ bhh,
    float* __restrict__ hnext)
{
    __shared__ float SB[25600];          // 100KB pool
    float* ctx_t = SB;                   // [128][67]
    float* h_t   = SB + 8576;            // [128][67]
    float* scr   = SB;                   // [8][128][25] (reused after compute)
    const int j0 = blockIdx.x * 4;
    const int tid = threadIdx.x;
    const int b = tid & 127;
    const int kq = __builtin_amdgcn_readfirstlane(tid >> 7);

    float accI[3][4] = {};
    float accH[3][4] = {};

    for (int kt = 0; kt < 8; ++kt) {
        const int koff = kt * 64;
        #pragma unroll
        for (int p = 0; p < 2; ++p) {
            int fid = tid + p * 1024;            // 2048 float4 = 128 rows x 16
            int row = fid >> 4, c4 = (fid & 15) * 4;
            float4 vc = *(const float4*)(ctx + (size_t)row * NH + koff + c4);
            float4 vh = *(const float4*)(hcur + (size_t)row * NH + koff + c4);
            ctx_t[row * 67 + c4 + 0] = vc.x; ctx_t[row * 67 + c4 + 1] = vc.y;
            ctx_t[row * 67 + c4 + 2] = vc.z; ctx_t[row * 67 + c4 + 3] = vc.w;
            h_t[row * 67 + c4 + 0] = vh.x; h_t[row * 67 + c4 + 1] = vh.y;
            h_t[row * 67 + c4 + 2] = vh.z; h_t[row * 67 + c4 + 3] = vh.w;
        }
        __syncthreads();
        #pragma unroll
        for (int kk = 0; kk < 8; ++kk) {
            int kl = kq * 8 + kk;
            float ac = ctx_t[b * 67 + kl];
            float ah = h_t[b * 67 + kl];
            int kg = koff + kl;
            #pragma unroll
            for (int g = 0; g < 3; ++g) {
                const float* wi = Wih + (size_t)(g * 512 + j0) * NH + kg;
                const float* wh = Whh + (size_t)(g * 512 + j0) * NH + kg;
                #pragma unroll
                for (int jo = 0; jo < 4; ++jo) {
                    accI[g][jo] += ac * wi[jo * NH];
                    accH[g][jo] += ah * wh[jo * NH];
                }
            }
        }
        __syncthreads();
    }

    // partials -> LDS (overlaps A-tiles; safe: all compute done, synced above)
    {
        float* p = &scr[(size_t)(kq * 128 + b) * 25];
        #pragma unroll
        for (int g = 0; g < 3; ++g)
            #pragma unroll
            for (int jo = 0; jo < 4; ++jo) {
                p[g * 4 + jo]      = accI[g][jo];
                p[12 + g * 4 + jo] = accH[g][jo];
            }
    }
    __syncthreads();

    if (tid < 512) {
        const int bb = tid & 127, jo = tid >> 7;
        float gi[3] = {0.f, 0.f, 0.f}, gh[3] = {0.f, 0.f, 0.f};
        #pragma unroll
        for (int q = 0; q < 8; ++q) {
            const float* p = &scr[(size_t)(q * 128 + bb) * 25];
            #pragma unroll
            for (int g = 0; g < 3; ++g) {
                gi[g] += p[g * 4 + jo];
                gh[g] += p[12 + g * 4 + jo];
            }
        }
        const int j = j0 + jo;
        float ir  = gi[0] + bih[j];
        float iz  = gi[1] + bih[512 + j];
        float in_ = gi[2] + bih[1024 + j];
        float hr  = gh[0] + bhh[j];
        float hz  = gh[1] + bhh[512 + j];
        float hnn = gh[2] + bhh[1024 + j];
        float r = fast_sigmoid(ir + hr);
        float z = fast_sigmoid(iz + hz);
        float ng = fast_tanh(in_ + r * hnn);
        float hv = hcur[(size_t)bb * NH + j];
        hnext[(size_t)bb * NH + j] = (1.f - z) * ng + z * hv;
    }
}

// ---------------------------------------------------------------------------
__global__ __launch_bounds__(256) void k_gen(const float* __restrict__ hid,
                                             const float* __restrict__ Wgen,
                                             const float* __restrict__ bgen,
                                             float* __restrict__ out) {
    __shared__ float As[32][36];
    __shared__ float Bs[32][97];
    const int m0 = blockIdx.x * 32;
    const int tid = threadIdx.x;
    const int tx = tid & 31, ty = tid >> 5;
    float acc[4][3] = {};
    for (int k0 = 0; k0 < 512; k0 += 32) {
        {
            int mm = tid >> 3, kq = (tid & 7) << 2;
            int m = m0 + mm, s = m & 31, b = m >> 5;
            float4 v = *(const float4*)(hid + (size_t)(s + 1) * 65536 + b * 512 + k0 + kq);
            *(float4*)(&As[mm][kq]) = v;
        }
        #pragma unroll
        for (int i = 0; i < 3; ++i) {
            int f4 = tid + i * 256;
            int nn = f4 >> 3, kq = (f4 & 7) << 2;
            float4 v = *(const float4*)(Wgen + (size_t)nn * 512 + k0 + kq);
            Bs[kq + 0][nn] = v.x; Bs[kq + 1][nn] = v.y;
            Bs[kq + 2][nn] = v.z; Bs[kq + 3][nn] = v.w;
        }
        __syncthreads();
        #pragma unroll
        for (int kk = 0; kk < 32; ++kk) {
            float bv[3];
            #pragma unroll
            for (int j = 0; j < 3; ++j) bv[j] = Bs[kk][tx * 3 + j];
            #pragma unroll
            for (int i = 0; i < 4; ++i) {
                float a = As[ty * 4 + i][kk];
                #pragma unroll
                for (int j = 0; j < 3; ++j) acc[i][j] += a * bv[j];
            }
        }
        __syncthreads();
    }
    #pragma unroll
    for (int i = 0; i < 4; ++i)
        #pragma unroll
        for (int j = 0; j < 3; ++j)
            out[(size_t)(m0 + ty * 4 + i) * NOUT + tx * 3 + j] = acc[i][j] + bgen[tx * 3 + j];
}

// ---------------------------------------------------------------------------
extern "C" void kernel_launch(void* const* d_in, const int* in_sizes, int n_in,
                              void* d_out, int out_size, void* d_ws, size_t ws_size,
                              hipStream_t stream) {
    const float* feats  = (const float*)d_in[0];
    const float* Wi2h   = (const float*)d_in[2];
    const float* Wh2h   = (const float*)d_in[3];
    const float* bh2h   = (const float*)d_in[4];
    const float* Wscore = (const float*)d_in[5];
    const float* Wih    = (const float*)d_in[6];
    const float* Whh    = (const float*)d_in[7];
    const float* bih    = (const float*)d_in[8];
    const float* bhh    = (const float*)d_in[9];
    const float* Wgen   = (const float*)d_in[10];
    const float* bgen   = (const float*)d_in[11];
    float* out = (float*)d_out;

    // ws (float slots): fp_bf(8388608) hid(2162688) ctx(65536) Wb(131072)
    //                   Fb/featsb(8388608)  -> 76.7 MB total
    float* ws  = (float*)d_ws;
    unsigned short* fp_bf = (unsigned short*)ws;
    float* hid  = ws + 8388608;
    float* ctxb = hid + 2162688;
    unsigned short* Wb     = (unsigned short*)(ctxb + 65536);
    unsigned short* Fb     = (unsigned short*)(ctxb + 65536 + 131072);
    unsigned short* featsb = Fb;    // reuses Fb space after k_fp_mfma

    hipMemsetAsync(hid, 0, 65536 * sizeof(float), stream);   // h0 = 0
    k_w2bf<<<64, 256, 0, stream>>>(Wi2h, Wb);
    k_feats2bf<<<4096, 256, 0, stream>>>(feats, Fb);
    k_fp_mfma<<<512, 256, 0, stream>>>(Wb, Fb, fp_bf);
    k_fcopy<<<4096, 1024, 0, stream>>>(feats, featsb);

    for (int s = 0; s < NSTEPS; ++s) {
        const float* h = hid + (size_t)s * 65536;
        float* hn      = hid + (size_t)(s + 1) * 65536;
        k_att<<<128, 1024, 0, stream>>>(fp_bf, featsb, h, Wh2h, bh2h, Wscore, ctxb);
        k_gru<<<128, 1024, 0, stream>>>(ctxb, h, Wih, Whh, bih, bhh, hn);
    }
    k_gen<<<128, 256, 0, stream>>>(hid, Wgen, bgen, out);
}

// Round 8
// 1664.889 us; speedup vs baseline: 13.5932x; 2.3287x over previous
//
#include <hip/hip_runtime.h>
#include <math.h>

#define NBATCH 128
#define NTIME  256
#define NCH    512
#define NH     512
#define NSTEPS 32
#define NOUT   96
#define MTOT   32768

typedef __attribute__((ext_vector_type(8))) short short8v;
typedef __attribute__((ext_vector_type(4))) float f32x4;

__device__ __forceinline__ float fast_tanh(float x) {
    x = fminf(fmaxf(x, -30.f), 30.f);
    float u = __expf(2.f * x);
    return (u - 1.f) / (u + 1.f);
}
__device__ __forceinline__ float fast_sigmoid(float x) {
    x = fminf(fmaxf(x, -30.f), 30.f);
    return 1.f / (1.f + __expf(-x));
}
__device__ __forceinline__ float wave_reduce_sum(float s) {
    #pragma unroll
    for (int off = 32; off; off >>= 1) s += __shfl_xor(s, off, 64);
    return s;
}
__device__ __forceinline__ float wave_reduce_max(float s) {
    #pragma unroll
    for (int off = 32; off; off >>= 1) s = fmaxf(s, __shfl_xor(s, off, 64));
    return s;
}
__device__ __forceinline__ unsigned short f2bf(float f) {
    unsigned u = __builtin_bit_cast(unsigned, f);
    return (unsigned short)((u + 0x7FFFu + ((u >> 16) & 1u)) >> 16);
}
__device__ __forceinline__ float bflo(unsigned u) {
    return __builtin_bit_cast(float, u << 16);
}
__device__ __forceinline__ float bfhi(unsigned u) {
    return __builtin_bit_cast(float, u & 0xFFFF0000u);
}

// ---------------------------------------------------------------------------
// Wi2h fp32 [512][512] -> bf16 same layout
__global__ __launch_bounds__(256) void k_w2bf(const float* __restrict__ W,
                                              unsigned short* __restrict__ Wb) {
    #pragma unroll
    for (int r = 0; r < 4; ++r) {
        int idx = (blockIdx.x * 256 + threadIdx.x) + r * 16384;
        float4 v = *(const float4*)(W + (size_t)idx * 4);
        ushort4 o;
        o.x = f2bf(v.x); o.y = f2bf(v.y); o.z = f2bf(v.z); o.w = f2bf(v.w);
        *(ushort4*)(Wb + (size_t)idx * 4) = o;
    }
}

// ---------------------------------------------------------------------------
// Wgb = concat(Wih, Whh) fp32 [3072][512] -> bf16. 384 blocks x 256, 4 f4 each.
__global__ __launch_bounds__(256) void k_wg2bf(const float* __restrict__ Wih,
                                               const float* __restrict__ Whh,
                                               unsigned short* __restrict__ Wgb) {
    #pragma unroll
    for (int r = 0; r < 4; ++r) {
        int idx = (blockIdx.x * 256 + threadIdx.x) + r * 98304;   // f4 idx, 393216 total
        const float* src = (idx < 196608) ? (Wih + (size_t)idx * 4)
                                          : (Whh + (size_t)(idx - 196608) * 4);
        float4 v = *(const float4*)src;
        ushort4 o;
        o.x = f2bf(v.x); o.y = f2bf(v.y); o.z = f2bf(v.z); o.w = f2bf(v.w);
        *(ushort4*)(Wgb + (size_t)idx * 4) = o;
    }
}

// ---------------------------------------------------------------------------
// feats fp32 [k=512][m=32768] -> featsT bf16 [m][k]
__global__ __launch_bounds__(256) void k_feats2bf(const float* __restrict__ feats,
                                                  unsigned short* __restrict__ Fb) {
    __shared__ float tl[64][65];
    const int m0 = (blockIdx.x & 511) * 64;
    const int k0 = (blockIdx.x >> 9) * 64;
    const int tid = threadIdx.x;
    #pragma unroll
    for (int p = 0; p < 4; ++p) {
        int fid = tid + p * 256;
        int row = fid >> 4, c4 = fid & 15;
        float4 v = *(const float4*)(feats + (size_t)(k0 + row) * MTOT + m0 + c4 * 4);
        tl[row][c4 * 4 + 0] = v.x; tl[row][c4 * 4 + 1] = v.y;
        tl[row][c4 * 4 + 2] = v.z; tl[row][c4 * 4 + 3] = v.w;
    }
    __syncthreads();
    #pragma unroll
    for (int p = 0; p < 4; ++p) {
        int cid = tid + p * 256;
        int mm = cid >> 4, ch = cid & 15;
        ushort4 o;
        o.x = f2bf(tl[ch * 4 + 0][mm]);
        o.y = f2bf(tl[ch * 4 + 1][mm]);
        o.z = f2bf(tl[ch * 4 + 2][mm]);
        o.w = f2bf(tl[ch * 4 + 3][mm]);
        *(ushort4*)(Fb + (size_t)(m0 + mm) * 512 + k0 + ch * 4) = o;
    }
}

// ---------------------------------------------------------------------------
// feats fp32 [c][b][t] -> bf16 same layout (runs AFTER k_fp_mfma; reuses Fb space)
__global__ __launch_bounds__(1024) void k_fcopy(const float* __restrict__ f,
                                                unsigned short* __restrict__ o) {
    int gid = blockIdx.x * 1024 + threadIdx.x;
    float4 v = *(const float4*)(f + (size_t)gid * 4);
    ushort4 s;
    s.x = f2bf(v.x); s.y = f2bf(v.y); s.z = f2bf(v.z); s.w = f2bf(v.w);
    *(ushort4*)(o + (size_t)gid * 4) = s;
}

// ---------------------------------------------------------------------------
// MFMA GEMM: fp[m][h] = sum_k featsT[m][k] * Wi2h[h][k]  (bf16 in, bf16 out)
__global__ __launch_bounds__(256) void k_fp_mfma(const unsigned short* __restrict__ Wb,
                                                 const unsigned short* __restrict__ Fb,
                                                 unsigned short* __restrict__ fp_bf) {
    __shared__ char SB[49152];
    unsigned short* As = (unsigned short*)SB;            // [128 h][64 k]
    unsigned short* Bs = (unsigned short*)(SB + 16384);  // [256 m][64 k]
    float* tl = (float*)SB;                              // [256 m][33]
    const int m0 = (blockIdx.x & 127) * 256;
    const int h0 = (blockIdx.x >> 7) * 128;
    const int tid = threadIdx.x;
    const int lane = tid & 63, wid = tid >> 6;
    const int wh = wid & 1, wm = wid >> 1;
    f32x4 acc[4][8];
    #pragma unroll
    for (int i = 0; i < 4; ++i)
        #pragma unroll
        for (int j = 0; j < 8; ++j) acc[i][j] = (f32x4)0.f;

    for (int k0 = 0; k0 < 512; k0 += 64) {
        #pragma unroll
        for (int i = 0; i < 4; ++i) {
            int cid = tid + i * 256;
            int row = cid >> 3, ch = cid & 7;
            uint4 v = *(const uint4*)(Wb + (size_t)(h0 + row) * 512 + k0 + ch * 8);
            *(uint4*)(As + row * 64 + ((ch ^ (row & 7)) << 3)) = v;
        }
        #pragma unroll
        for (int i = 0; i < 8; ++i) {
            int cid = tid + i * 256;
            int row = cid >> 3, ch = cid & 7;
            uint4 v = *(const uint4*)(Fb + (size_t)(m0 + row) * 512 + k0 + ch * 8);
            *(uint4*)(Bs + row * 64 + ((ch ^ (row & 7)) << 3)) = v;
        }
        __syncthreads();
        #pragma unroll
        for (int ks = 0; ks < 2; ++ks) {
            short8v a[4], b[8];
            #pragma unroll
            for (int hf = 0; hf < 4; ++hf) {
                int row = wh * 64 + hf * 16 + (lane & 15);
                int ch = ks * 4 + (lane >> 4);
                a[hf] = *(const short8v*)(As + row * 64 + ((ch ^ (row & 7)) << 3));
            }
            #pragma unroll
            for (int mf = 0; mf < 8; ++mf) {
                int row = wm * 128 + mf * 16 + (lane & 15);
                int ch = ks * 4 + (lane >> 4);
                b[mf] = *(const short8v*)(Bs + row * 64 + ((ch ^ (row & 7)) << 3));
            }
            #pragma unroll
            for (int hf = 0; hf < 4; ++hf)
                #pragma unroll
                for (int mf = 0; mf < 8; ++mf)
                    acc[hf][mf] = __builtin_amdgcn_mfma_f32_16x16x32_bf16(
                        a[hf], b[mf], acc[hf][mf], 0, 0, 0);
        }
        __syncthreads();
    }
    #pragma unroll
    for (int hf = 0; hf < 4; ++hf) {
        #pragma unroll
        for (int mf = 0; mf < 8; ++mf) {
            int ml = wm * 128 + mf * 16 + (lane & 15);
            int col = wh * 16 + (lane >> 4) * 4;
            tl[ml * 33 + col + 0] = acc[hf][mf][0];
            tl[ml * 33 + col + 1] = acc[hf][mf][1];
            tl[ml * 33 + col + 2] = acc[hf][mf][2];
            tl[ml * 33 + col + 3] = acc[hf][mf][3];
        }
        __syncthreads();
        #pragma unroll
        for (int mi = 0; mi < 8; ++mi) {
            int ml = (tid >> 3) + mi * 32;
            int hl4 = (tid & 7) * 4;
            float v0 = tl[ml * 33 + hl4 + 0];
            float v1 = tl[ml * 33 + hl4 + 1];
            float v2 = tl[ml * 33 + hl4 + 2];
            float v3 = tl[ml * 33 + hl4 + 3];
            int hg = h0 + ((hl4 < 16) ? (hf * 16 + hl4) : (64 + hf * 16 + hl4 - 16));
            ushort4 o;
            o.x = f2bf(v0); o.y = f2bf(v1); o.z = f2bf(v2); o.w = f2bf(v3);
            *(ushort4*)(fp_bf + (size_t)(m0 + ml) * 512 + hg) = o;
        }
        __syncthreads();
    }
}

// ---------------------------------------------------------------------------
// Transpose Wh2h[512][512] -> WTb[k][j] bf16  (one-time)
__global__ __launch_bounds__(256) void k_wt(const float* __restrict__ W,
                                            unsigned short* __restrict__ WTb) {
    __shared__ float tl[32][33];
    const int bi = blockIdx.x & 15, bj = blockIdx.x >> 4;
    const int tx = threadIdx.x & 31, ty8 = threadIdx.x >> 5;
    #pragma unroll
    for (int i = 0; i < 4; ++i) {
        int r = ty8 * 4 + i;
        tl[r][tx] = W[(size_t)(bj * 32 + r) * NH + bi * 32 + tx];
    }
    __syncthreads();
    #pragma unroll
    for (int i = 0; i < 4; ++i) {
        int c = ty8 * 4 + i;
        WTb[(size_t)(bi * 32 + c) * NH + bj * 32 + tx] = f2bf(tl[tx][c]);
    }
}

// ---------------------------------------------------------------------------
__global__ __launch_bounds__(1024) void k_hp0(const float* __restrict__ bh2h,
                                              float* __restrict__ hp) {
    int i = blockIdx.x * 1024 + threadIdx.x;
    hp[i] = bh2h[i & 511];
}

// ---------------------------------------------------------------------------
// e[b][t] = sum_h tanh(fp[b][t][h] + hp[b][h]) * wscore[h]   (fp in bf16)
// 512 blocks x 512: b = blk>>2, t0 = (blk&3)*64; wave -> 8 t's.
__global__ __launch_bounds__(512) void k_e(const unsigned short* __restrict__ fp_bf,
                                           const float* __restrict__ hp,
                                           const float* __restrict__ wscore,
                                           float* __restrict__ e) {
    const int b = blockIdx.x >> 2;
    const int t0 = (blockIdx.x & 3) * 64;
    const int tid = threadIdx.x;
    const int lane = tid & 63, w = tid >> 6;
    float4 h0 = *(const float4*)(hp + (size_t)b * NH + lane * 8);
    float4 h1 = *(const float4*)(hp + (size_t)b * NH + lane * 8 + 4);
    float4 w0 = *(const float4*)(wscore + lane * 8);
    float4 w1 = *(const float4*)(wscore + lane * 8 + 4);
    #pragma unroll 2
    for (int it = 0; it < 8; ++it) {
        int t = t0 + w * 8 + it;
        uint4 v = *(const uint4*)(fp_bf + (size_t)(b * NTIME + t) * NH + lane * 8);
        float s = fast_tanh(bflo(v.x) + h0.x) * w0.x + fast_tanh(bfhi(v.x) + h0.y) * w0.y +
                  fast_tanh(bflo(v.y) + h0.z) * w0.z + fast_tanh(bfhi(v.y) + h0.w) * w0.w +
                  fast_tanh(bflo(v.z) + h1.x) * w1.x + fast_tanh(bfhi(v.z) + h1.y) * w1.y +
                  fast_tanh(bflo(v.w) + h1.z) * w1.z + fast_tanh(bfhi(v.w) + h1.w) * w1.w;
        s = wave_reduce_sum(s);
        if (lane == 0) e[b * NTIME + t] = s;
    }
}

// ---------------------------------------------------------------------------
// softmax(e[b]) + ctx[b][c] = sum_t featsb[c][b][t]*alpha[t] -> ctx_bf (bf16)
// 512 blocks x 512: b = blk>>2, c0 = (blk&3)*128; wave -> 16 c's.
__global__ __launch_bounds__(512) void k_ctx2(const float* __restrict__ e,
                                              const unsigned short* __restrict__ featsb,
                                              unsigned short* __restrict__ ctx_bf) {
    __shared__ float als[256];
    __shared__ float red[8];
    const int b = blockIdx.x >> 2;
    const int c0 = (blockIdx.x & 3) * 128;
    const int tid = threadIdx.x;
    const int lane = tid & 63, w = tid >> 6;
    float v = (tid < 256) ? e[b * NTIME + tid] : -3.4e38f;
    float m = wave_reduce_max(v);
    if (lane == 0) red[w] = m;
    __syncthreads();
    m = red[0];
    #pragma unroll
    for (int i = 1; i < 8; ++i) m = fmaxf(m, red[i]);
    float ex = (tid < 256) ? __expf(v - m) : 0.f;
    float s = wave_reduce_sum(ex);
    __syncthreads();
    if (lane == 0) red[w] = s;
    __syncthreads();
    s = 0.f;
    #pragma unroll
    for (int i = 0; i < 8; ++i) s += red[i];
    if (tid < 256) als[tid] = ex / s;
    __syncthreads();

    float4 al = *(const float4*)&als[lane * 4];
    #pragma unroll 4
    for (int cc = 0; cc < 16; ++cc) {
        int c = c0 + w * 16 + cc;
        uint2 fv = *(const uint2*)(featsb + (size_t)(c * NBATCH + b) * NTIME + lane * 4);
        float sc = bflo(fv.x) * al.x + bfhi(fv.x) * al.y +
                   bflo(fv.y) * al.z + bfhi(fv.y) * al.w;
        sc = wave_reduce_sum(sc);
        if (lane == 0) ctx_bf[(size_t)b * NCH + c] = f2bf(sc);
    }
}

// ---------------------------------------------------------------------------
// Gates GEMM via MFMA: g2[j][b] = sum_k A[b][k] * Wgb[j][k], fp32 out.
// j in [0,3072): rows [0,1536) pair with ctx_bf, [1536,3072) with h_bf.
// 24 blocks x 256 (4 waves 2b x 2j); block tile 128b x 128j, BK=64.
// D mapping (verified in k_fp_mfma): D-row = A-rows (b) = (lane>>4)*4+reg,
// D-col = B-rows (j) = lane&15  -> f32x4 store hits 4 consecutive b.
__global__ __launch_bounds__(256) void k_gmfma(const unsigned short* __restrict__ ctx_bf,
                                               const unsigned short* __restrict__ h_bf,
                                               const unsigned short* __restrict__ Wgb,
                                               float* __restrict__ g2) {
    __shared__ unsigned short As[128 * 64];   // activations [128 b][64 k]
    __shared__ unsigned short Bs[128 * 64];   // weights     [128 j][64 k]
    const int j0 = blockIdx.x * 128;
    const unsigned short* A = (j0 < 1536) ? ctx_bf : h_bf;
    const int tid = threadIdx.x;
    const int lane = tid & 63, wid = tid >> 6;
    const int wb = wid & 1, wj = wid >> 1;
    f32x4 acc[4][4];
    #pragma unroll
    for (int i = 0; i < 4; ++i)
        #pragma unroll
        for (int j = 0; j < 4; ++j) acc[i][j] = (f32x4)0.f;

    for (int k0 = 0; k0 < 512; k0 += 64) {
        #pragma unroll
        for (int i = 0; i < 4; ++i) {
            int cid = tid + i * 256;               // 1024: 128 rows x 8 chunks
            int row = cid >> 3, ch = cid & 7;
            uint4 va = *(const uint4*)(A + (size_t)row * 512 + k0 + ch * 8);
            *(uint4*)(As + row * 64 + ((ch ^ (row & 7)) << 3)) = va;
            uint4 vb = *(const uint4*)(Wgb + (size_t)(j0 + row) * 512 + k0 + ch * 8);
            *(uint4*)(Bs + row * 64 + ((ch ^ (row & 7)) << 3)) = vb;
        }
        __syncthreads();
        #pragma unroll
        for (int ks = 0; ks < 2; ++ks) {
            short8v a[4], b[4];
            #pragma unroll
            for (int f = 0; f < 4; ++f) {
                int rowa = wb * 64 + f * 16 + (lane & 15);
                int rowb = wj * 64 + f * 16 + (lane & 15);
                int ch = ks * 4 + (lane >> 4);
                a[f] = *(const short8v*)(As + rowa * 64 + ((ch ^ (rowa & 7)) << 3));
                b[f] = *(const short8v*)(Bs + rowb * 64 + ((ch ^ (rowb & 7)) << 3));
            }
            #pragma unroll
            for (int bf = 0; bf < 4; ++bf)
                #pragma unroll
                for (int jf = 0; jf < 4; ++jf)
                    acc[bf][jf] = __builtin_amdgcn_mfma_f32_16x16x32_bf16(
                        a[bf], b[jf], acc[bf][jf], 0, 0, 0);
        }
        __syncthreads();
    }
    #pragma unroll
    for (int bf = 0; bf < 4; ++bf) {
        int b = wb * 64 + bf * 16 + (lane >> 4) * 4;
        #pragma unroll
        for (int jf = 0; jf < 4; ++jf) {
            int j = j0 + wj * 64 + jf * 16 + (lane & 15);
            *(f32x4*)(g2 + (size_t)j * NBATCH + b) = acc[bf][jf];
        }
    }
}

// ---------------------------------------------------------------------------
// Fused GRU-combine + next hp (WTb bf16). Writes h_bf for next step's gates.
__global__ __launch_bounds__(1024) void k_comb_hp(const float* __restrict__ g2,
                                                  const float* __restrict__ hprev,
                                                  float* __restrict__ hidn,
                                                  unsigned short* __restrict__ h_bf,
                                                  const float* __restrict__ bih,
                                                  const float* __restrict__ bhh,
                                                  const unsigned short* __restrict__ WTb,
                                                  const float* __restrict__ bh2h,
                                                  float* __restrict__ hp) {
    __shared__ float h_s[4 * 512];
    __shared__ float scr2[16 * 4 * 16 * 4];
    const int blk = blockIdx.x;
    const int b0 = (blk >> 3) * 4;
    const int jbase = (blk & 7) * 64;
    const int tid = threadIdx.x;
    #pragma unroll
    for (int rep = 0; rep < 2; ++rep) {
        int idx = tid + rep * 1024;
        int bi = idx & 3, kk = idx >> 2;
        int b = b0 + bi;
        float ir  = g2[(size_t)(0 * 512 + kk) * NBATCH + b] + bih[kk];
        float iz  = g2[(size_t)(1 * 512 + kk) * NBATCH + b] + bih[512 + kk];
        float in_ = g2[(size_t)(2 * 512 + kk) * NBATCH + b] + bih[1024 + kk];
        float hr  = g2[(size_t)(3 * 512 + kk) * NBATCH + b] + bhh[kk];
        float hz  = g2[(size_t)(4 * 512 + kk) * NBATCH + b] + bhh[512 + kk];
        float hn  = g2[(size_t)(5 * 512 + kk) * NBATCH + b] + bhh[1024 + kk];
        float r = fast_sigmoid(ir + hr);
        float z = fast_sigmoid(iz + hz);
        float ng = fast_tanh(in_ + r * hn);
        float hv = hprev[(size_t)b * NH + kk];
        float hnew = (1.f - z) * ng + z * hv;
        h_s[bi * 512 + kk] = hnew;
        if ((blk & 7) == 0) {
            hidn[(size_t)b * NH + kk] = hnew;
            h_bf[(size_t)b * NH + kk] = f2bf(hnew);
        }
    }
    __syncthreads();
    {
        const int jq = tid & 15, bi = (tid >> 4) & 3, kq = tid >> 6;
        const int j = jbase + jq * 4;
        float4 acc = make_float4(0.f, 0.f, 0.f, 0.f);
        #pragma unroll 8
        for (int kk = 0; kk < 32; ++kk) {
            int k = kq * 32 + kk;
            uint2 wq = *(const uint2*)(WTb + (size_t)k * NH + j);
            float hv = h_s[bi * 512 + k];
            acc.x += hv * bflo(wq.x); acc.y += hv * bfhi(wq.x);
            acc.z += hv * bflo(wq.y); acc.w += hv * bfhi(wq.y);
        }
        *(float4*)&scr2[((kq * 4 + bi) * 16 + jq) * 4] = acc;
    }
    __syncthreads();
    if (tid < 64) {
        const int bi = tid >> 4, jq = tid & 15;
        float4 sum = make_float4(0.f, 0.f, 0.f, 0.f);
        #pragma unroll
        for (int kq = 0; kq < 16; ++kq) {
            float4 p = *(const float4*)&scr2[((kq * 4 + bi) * 16 + jq) * 4];
            sum.x += p.x; sum.y += p.y; sum.z += p.z; sum.w += p.w;
        }
        int j = jbase + jq * 4;
        float4 bb = *(const float4*)(bh2h + j);
        sum.x += bb.x; sum.y += bb.y; sum.z += bb.z; sum.w += bb.w;
        *(float4*)(hp + (size_t)(b0 + bi) * NH + j) = sum;
    }
}

// ---------------------------------------------------------------------------
__global__ __launch_bounds__(256) void k_gen(const float* __restrict__ hid,
                                             const float* __restrict__ Wgen,
                                             const float* __restrict__ bgen,
                                             float* __restrict__ out) {
    __shared__ float As[32][36];
    __shared__ float Bs[32][97];
    const int m0 = blockIdx.x * 32;
    const int tid = threadIdx.x;
    const int tx = tid & 31, ty = tid >> 5;
    float acc[4][3] = {};
    for (int k0 = 0; k0 < 512; k0 += 32) {
        {
            int mm = tid >> 3, kq = (tid & 7) << 2;
            int m = m0 + mm, s = m & 31, b = m >> 5;
            float4 v = *(const float4*)(hid + (size_t)(s + 1) * 65536 + b * 512 + k0 + kq);
            *(float4*)(&As[mm][kq]) = v;
        }
        #pragma unroll
        for (int i = 0; i < 3; ++i) {
            int f4 = tid + i * 256;
            int nn = f4 >> 3, kq = (f4 & 7) << 2;
            float4 v = *(const float4*)(Wgen + (size_t)nn * 512 + k0 + kq);
            Bs[kq + 0][nn] = v.x; Bs[kq + 1][nn] = v.y;
            Bs[kq + 2][nn] = v.z; Bs[kq + 3][nn] = v.w;
        }
        __syncthreads();
        #pragma unroll
        for (int kk = 0; kk < 32; ++kk) {
            float bv[3];
            #pragma unroll
            for (int j = 0; j < 3; ++j) bv[j] = Bs[kk][tx * 3 + j];
            #pragma unroll
            for (int i = 0; i < 4; ++i) {
                float a = As[ty * 4 + i][kk];
                #pragma unroll
                for (int j = 0; j < 3; ++j) acc[i][j] += a * bv[j];
            }
        }
        __syncthreads();
    }
    #pragma unroll
    for (int i = 0; i < 4; ++i)
        #pragma unroll
        for (int j = 0; j < 3; ++j)
            out[(size_t)(m0 + ty * 4 + i) * NOUT + tx * 3 + j] = acc[i][j] + bgen[tx * 3 + j];
}

// ---------------------------------------------------------------------------
extern "C" void kernel_launch(void* const* d_in, const int* in_sizes, int n_in,
                              void* d_out, int out_size, void* d_ws, size_t ws_size,
                              hipStream_t stream) {
    const float* feats  = (const float*)d_in[0];
    const float* Wi2h   = (const float*)d_in[2];
    const float* Wh2h   = (const float*)d_in[3];
    const float* bh2h   = (const float*)d_in[4];
    const float* Wscore = (const float*)d_in[5];
    const float* Wih    = (const float*)d_in[6];
    const float* Whh    = (const float*)d_in[7];
    const float* bih    = (const float*)d_in[8];
    const float* bhh    = (const float*)d_in[9];
    const float* Wgen   = (const float*)d_in[10];
    const float* bgen   = (const float*)d_in[11];
    float* out = (float*)d_out;

    // ws layout (float-slot offsets), ~80.5 MB total (ws proved >= 111 MB in r4):
    float* ws  = (float*)d_ws;
    unsigned short* fp_bf  = (unsigned short*)ws;                    // 16,777,216 bf16
    float*          hid    = ws + 8388608;                           // 2,162,688 f32
    float*          hpctx  = hid + 2162688;                          // 65,536 f32 (hp only)
    unsigned short* ctx_bf = (unsigned short*)(hpctx + 65536);       // 65,536 bf16
    unsigned short* h_bf   = (unsigned short*)(hpctx + 65536 + 32768);   // 65,536 bf16
    unsigned short* WTb    = (unsigned short*)(hpctx + 65536 + 65536);   // 262,144 bf16
    unsigned short* Wgb    = (unsigned short*)(hpctx + 65536 + 65536 + 131072); // 1,572,864 bf16
    unsigned short* Wb     = (unsigned short*)(hpctx + 65536 + 65536 + 131072 + 786432); // 262,144 bf16
    unsigned short* Fb     = (unsigned short*)(hpctx + 65536 + 65536 + 131072 + 786432 + 131072); // 16,777,216 bf16
    unsigned short* featsb = Fb;    // reuses Fb space after k_fp_mfma

    float* e  = out;                // aliases g2 head; disjoint lifetimes
    float* g2 = out;                // 6*512*128 = 393216 = out_size

    hipMemsetAsync(hid, 0, 65536 * sizeof(float), stream);       // h0 = 0
    hipMemsetAsync(h_bf, 0, 65536 * sizeof(unsigned short), stream); // h0_bf = 0
    k_wt<<<256, 256, 0, stream>>>(Wh2h, WTb);
    k_w2bf<<<64, 256, 0, stream>>>(Wi2h, Wb);
    k_wg2bf<<<384, 256, 0, stream>>>(Wih, Whh, Wgb);
    k_feats2bf<<<4096, 256, 0, stream>>>(feats, Fb);
    k_fp_mfma<<<512, 256, 0, stream>>>(Wb, Fb, fp_bf);
    k_fcopy<<<4096, 1024, 0, stream>>>(feats, featsb);           // after mfma: Fb dead
    k_hp0<<<64, 1024, 0, stream>>>(bh2h, hpctx);

    for (int s = 0; s < NSTEPS; ++s) {
        const float* h = hid + (size_t)s * 65536;
        float* hn      = hid + (size_t)(s + 1) * 65536;
        k_e<<<512, 512, 0, stream>>>(fp_bf, hpctx, Wscore, e);
        k_ctx2<<<512, 512, 0, stream>>>(e, featsb, ctx_bf);
        k_gmfma<<<24, 256, 0, stream>>>(ctx_bf, h_bf, Wgb, g2);
        k_comb_hp<<<256, 1024, 0, stream>>>(g2, h, hn, h_bf, bih, bhh, WTb, bh2h, hpctx);
    }
    k_gen<<<128, 256, 0, stream>>>(hid, Wgen, bgen, out);
}

// Round 9
// 1564.180 us; speedup vs baseline: 14.4684x; 1.0644x over previous
//
#include <hip/hip_runtime.h>
#include <math.h>

#define NBATCH 128
#define NTIME  256
#define NCH    512
#define NH     512
#define NSTEPS 32
#define NOUT   96
#define MTOT   32768

typedef __attribute__((ext_vector_type(8))) short short8v;
typedef __attribute__((ext_vector_type(4))) float f32x4;

__device__ __forceinline__ float fast_tanh(float x) {
    x = fminf(fmaxf(x, -30.f), 30.f);
    float u = __expf(2.f * x);
    return (u - 1.f) / (u + 1.f);
}
__device__ __forceinline__ float fast_sigmoid(float x) {
    x = fminf(fmaxf(x, -30.f), 30.f);
    return 1.f / (1.f + __expf(-x));
}
__device__ __forceinline__ float wave_reduce_sum(float s) {
    #pragma unroll
    for (int off = 32; off; off >>= 1) s += __shfl_xor(s, off, 64);
    return s;
}
__device__ __forceinline__ float wave_reduce_max(float s) {
    #pragma unroll
    for (int off = 32; off; off >>= 1) s = fmaxf(s, __shfl_xor(s, off, 64));
    return s;
}
__device__ __forceinline__ unsigned short f2bf(float f) {
    unsigned u = __builtin_bit_cast(unsigned, f);
    return (unsigned short)((u + 0x7FFFu + ((u >> 16) & 1u)) >> 16);
}
__device__ __forceinline__ float bflo(unsigned u) {
    return __builtin_bit_cast(float, u << 16);
}
__device__ __forceinline__ float bfhi(unsigned u) {
    return __builtin_bit_cast(float, u & 0xFFFF0000u);
}

// ---------------------------------------------------------------------------
// Wi2h fp32 [512][512] -> bf16 same layout
__global__ __launch_bounds__(256) void k_w2bf(const float* __restrict__ W,
                                              unsigned short* __restrict__ Wb) {
    #pragma unroll
    for (int r = 0; r < 4; ++r) {
        int idx = (blockIdx.x * 256 + threadIdx.x) + r * 16384;
        float4 v = *(const float4*)(W + (size_t)idx * 4);
        ushort4 o;
        o.x = f2bf(v.x); o.y = f2bf(v.y); o.z = f2bf(v.z); o.w = f2bf(v.w);
        *(ushort4*)(Wb + (size_t)idx * 4) = o;
    }
}

// ---------------------------------------------------------------------------
// Wgb = concat(Wih, Whh) fp32 [3072][512] -> bf16. 384 blocks x 256, 4 f4 each.
__global__ __launch_bounds__(256) void k_wg2bf(const float* __restrict__ Wih,
                                               const float* __restrict__ Whh,
                                               unsigned short* __restrict__ Wgb) {
    #pragma unroll
    for (int r = 0; r < 4; ++r) {
        int idx = (blockIdx.x * 256 + threadIdx.x) + r * 98304;   // f4 idx, 393216 total
        const float* src = (idx < 196608) ? (Wih + (size_t)idx * 4)
                                          : (Whh + (size_t)(idx - 196608) * 4);
        float4 v = *(const float4*)src;
        ushort4 o;
        o.x = f2bf(v.x); o.y = f2bf(v.y); o.z = f2bf(v.z); o.w = f2bf(v.w);
        *(ushort4*)(Wgb + (size_t)idx * 4) = o;
    }
}

// ---------------------------------------------------------------------------
// feats fp32 [k=512][m=32768] -> featsT bf16 [m][k]
__global__ __launch_bounds__(256) void k_feats2bf(const float* __restrict__ feats,
                                                  unsigned short* __restrict__ Fb) {
    __shared__ float tl[64][65];
    const int m0 = (blockIdx.x & 511) * 64;
    const int k0 = (blockIdx.x >> 9) * 64;
    const int tid = threadIdx.x;
    #pragma unroll
    for (int p = 0; p < 4; ++p) {
        int fid = tid + p * 256;
        int row = fid >> 4, c4 = fid & 15;
        float4 v = *(const float4*)(feats + (size_t)(k0 + row) * MTOT + m0 + c4 * 4);
        tl[row][c4 * 4 + 0] = v.x; tl[row][c4 * 4 + 1] = v.y;
        tl[row][c4 * 4 + 2] = v.z; tl[row][c4 * 4 + 3] = v.w;
    }
    __syncthreads();
    #pragma unroll
    for (int p = 0; p < 4; ++p) {
        int cid = tid + p * 256;
        int mm = cid >> 4, ch = cid & 15;
        ushort4 o;
        o.x = f2bf(tl[ch * 4 + 0][mm]);
        o.y = f2bf(tl[ch * 4 + 1][mm]);
        o.z = f2bf(tl[ch * 4 + 2][mm]);
        o.w = f2bf(tl[ch * 4 + 3][mm]);
        *(ushort4*)(Fb + (size_t)(m0 + mm) * 512 + k0 + ch * 4) = o;
    }
}

// ---------------------------------------------------------------------------
// feats fp32 [c][b][t] -> bf16 same layout (runs AFTER k_fp_mfma; reuses Fb space)
__global__ __launch_bounds__(1024) void k_fcopy(const float* __restrict__ f,
                                                unsigned short* __restrict__ o) {
    int gid = blockIdx.x * 1024 + threadIdx.x;
    float4 v = *(const float4*)(f + (size_t)gid * 4);
    ushort4 s;
    s.x = f2bf(v.x); s.y = f2bf(v.y); s.z = f2bf(v.z); s.w = f2bf(v.w);
    *(ushort4*)(o + (size_t)gid * 4) = s;
}

// ---------------------------------------------------------------------------
// MFMA GEMM: fp[m][h] = sum_k featsT[m][k] * Wi2h[h][k]  (bf16 in, bf16 out)
__global__ __launch_bounds__(256) void k_fp_mfma(const unsigned short* __restrict__ Wb,
                                                 const unsigned short* __restrict__ Fb,
                                                 unsigned short* __restrict__ fp_bf) {
    __shared__ char SB[49152];
    unsigned short* As = (unsigned short*)SB;            // [128 h][64 k]
    unsigned short* Bs = (unsigned short*)(SB + 16384);  // [256 m][64 k]
    float* tl = (float*)SB;                              // [256 m][33]
    const int m0 = (blockIdx.x & 127) * 256;
    const int h0 = (blockIdx.x >> 7) * 128;
    const int tid = threadIdx.x;
    const int lane = tid & 63, wid = tid >> 6;
    const int wh = wid & 1, wm = wid >> 1;
    f32x4 acc[4][8];
    #pragma unroll
    for (int i = 0; i < 4; ++i)
        #pragma unroll
        for (int j = 0; j < 8; ++j) acc[i][j] = (f32x4)0.f;

    for (int k0 = 0; k0 < 512; k0 += 64) {
        #pragma unroll
        for (int i = 0; i < 4; ++i) {
            int cid = tid + i * 256;
            int row = cid >> 3, ch = cid & 7;
            uint4 v = *(const uint4*)(Wb + (size_t)(h0 + row) * 512 + k0 + ch * 8);
            *(uint4*)(As + row * 64 + ((ch ^ (row & 7)) << 3)) = v;
        }
        #pragma unroll
        for (int i = 0; i < 8; ++i) {
            int cid = tid + i * 256;
            int row = cid >> 3, ch = cid & 7;
            uint4 v = *(const uint4*)(Fb + (size_t)(m0 + row) * 512 + k0 + ch * 8);
            *(uint4*)(Bs + row * 64 + ((ch ^ (row & 7)) << 3)) = v;
        }
        __syncthreads();
        #pragma unroll
        for (int ks = 0; ks < 2; ++ks) {
            short8v a[4], b[8];
            #pragma unroll
            for (int hf = 0; hf < 4; ++hf) {
                int row = wh * 64 + hf * 16 + (lane & 15);
                int ch = ks * 4 + (lane >> 4);
                a[hf] = *(const short8v*)(As + row * 64 + ((ch ^ (row & 7)) << 3));
            }
            #pragma unroll
            for (int mf = 0; mf < 8; ++mf) {
                int row = wm * 128 + mf * 16 + (lane & 15);
                int ch = ks * 4 + (lane >> 4);
                b[mf] = *(const short8v*)(Bs + row * 64 + ((ch ^ (row & 7)) << 3));
            }
            #pragma unroll
            for (int hf = 0; hf < 4; ++hf)
                #pragma unroll
                for (int mf = 0; mf < 8; ++mf)
                    acc[hf][mf] = __builtin_amdgcn_mfma_f32_16x16x32_bf16(
                        a[hf], b[mf], acc[hf][mf], 0, 0, 0);
        }
        __syncthreads();
    }
    #pragma unroll
    for (int hf = 0; hf < 4; ++hf) {
        #pragma unroll
        for (int mf = 0; mf < 8; ++mf) {
            int ml = wm * 128 + mf * 16 + (lane & 15);
            int col = wh * 16 + (lane >> 4) * 4;
            tl[ml * 33 + col + 0] = acc[hf][mf][0];
            tl[ml * 33 + col + 1] = acc[hf][mf][1];
            tl[ml * 33 + col + 2] = acc[hf][mf][2];
            tl[ml * 33 + col + 3] = acc[hf][mf][3];
        }
        __syncthreads();
        #pragma unroll
        for (int mi = 0; mi < 8; ++mi) {
            int ml = (tid >> 3) + mi * 32;
            int hl4 = (tid & 7) * 4;
            float v0 = tl[ml * 33 + hl4 + 0];
            float v1 = tl[ml * 33 + hl4 + 1];
            float v2 = tl[ml * 33 + hl4 + 2];
            float v3 = tl[ml * 33 + hl4 + 3];
            int hg = h0 + ((hl4 < 16) ? (hf * 16 + hl4) : (64 + hf * 16 + hl4 - 16));
            ushort4 o;
            o.x = f2bf(v0); o.y = f2bf(v1); o.z = f2bf(v2); o.w = f2bf(v3);
            *(ushort4*)(fp_bf + (size_t)(m0 + ml) * 512 + hg) = o;
        }
        __syncthreads();
    }
}

// ---------------------------------------------------------------------------
// Transpose Wh2h[512][512] -> WTb[k][j] bf16  (one-time)
__global__ __launch_bounds__(256) void k_wt(const float* __restrict__ W,
                                            unsigned short* __restrict__ WTb) {
    __shared__ float tl[32][33];
    const int bi = blockIdx.x & 15, bj = blockIdx.x >> 4;
    const int tx = threadIdx.x & 31, ty8 = threadIdx.x >> 5;
    #pragma unroll
    for (int i = 0; i < 4; ++i) {
        int r = ty8 * 4 + i;
        tl[r][tx] = W[(size_t)(bj * 32 + r) * NH + bi * 32 + tx];
    }
    __syncthreads();
    #pragma unroll
    for (int i = 0; i < 4; ++i) {
        int c = ty8 * 4 + i;
        WTb[(size_t)(bi * 32 + c) * NH + bj * 32 + tx] = f2bf(tl[tx][c]);
    }
}

// ---------------------------------------------------------------------------
__global__ __launch_bounds__(1024) void k_hp0(const float* __restrict__ bh2h,
                                              float* __restrict__ hp) {
    int i = blockIdx.x * 1024 + threadIdx.x;
    hp[i] = bh2h[i & 511];
}

// ---------------------------------------------------------------------------
// e[b][t] = sum_h tanh(fp[b][t][h] + hp[b][h]) * wscore[h]   (fp in bf16)
// 1024 blocks x 512 (4 blocks/CU -> 32 waves/CU): b = blk>>3, t0 = (blk&7)*32;
// wave -> 4 t's, all loads hoisted/issued before compute.
__global__ __launch_bounds__(512) void k_e(const unsigned short* __restrict__ fp_bf,
                                           const float* __restrict__ hp,
                                           const float* __restrict__ wscore,
                                           float* __restrict__ e) {
    const int b = blockIdx.x >> 3;
    const int t0 = (blockIdx.x & 7) * 32;
    const int tid = threadIdx.x;
    const int lane = tid & 63, w = tid >> 6;
    float4 h0 = *(const float4*)(hp + (size_t)b * NH + lane * 8);
    float4 h1 = *(const float4*)(hp + (size_t)b * NH + lane * 8 + 4);
    float4 w0 = *(const float4*)(wscore + lane * 8);
    float4 w1 = *(const float4*)(wscore + lane * 8 + 4);
    const unsigned short* base = fp_bf + (size_t)(b * NTIME + t0 + w * 4) * NH + lane * 8;
    uint4 v0 = *(const uint4*)(base);
    uint4 v1 = *(const uint4*)(base + NH);
    uint4 v2 = *(const uint4*)(base + 2 * NH);
    uint4 v3 = *(const uint4*)(base + 3 * NH);
    uint4 vv[4] = {v0, v1, v2, v3};
    #pragma unroll
    for (int it = 0; it < 4; ++it) {
        uint4 v = vv[it];
        float s = fast_tanh(bflo(v.x) + h0.x) * w0.x + fast_tanh(bfhi(v.x) + h0.y) * w0.y +
                  fast_tanh(bflo(v.y) + h0.z) * w0.z + fast_tanh(bfhi(v.y) + h0.w) * w0.w +
                  fast_tanh(bflo(v.z) + h1.x) * w1.x + fast_tanh(bfhi(v.z) + h1.y) * w1.y +
                  fast_tanh(bflo(v.w) + h1.z) * w1.z + fast_tanh(bfhi(v.w) + h1.w) * w1.w;
        s = wave_reduce_sum(s);
        if (lane == 0) e[b * NTIME + t0 + w * 4 + it] = s;
    }
}

// ---------------------------------------------------------------------------
// softmax(e[b]) + ctx[b][c] = sum_t featsb[c][b][t]*alpha[t] -> ctx_bf (bf16)
// 1024 blocks x 512: b = blk>>3, c0 = (blk&7)*64; wave -> 8 c's.
__global__ __launch_bounds__(512) void k_ctx2(const float* __restrict__ e,
                                              const unsigned short* __restrict__ featsb,
                                              unsigned short* __restrict__ ctx_bf) {
    __shared__ float als[256];
    __shared__ float red[8];
    const int b = blockIdx.x >> 3;
    const int c0 = (blockIdx.x & 7) * 64;
    const int tid = threadIdx.x;
    const int lane = tid & 63, w = tid >> 6;
    float v = (tid < 256) ? e[b * NTIME + tid] : -3.4e38f;
    float m = wave_reduce_max(v);
    if (lane == 0) red[w] = m;
    __syncthreads();
    m = red[0];
    #pragma unroll
    for (int i = 1; i < 8; ++i) m = fmaxf(m, red[i]);
    float ex = (tid < 256) ? __expf(v - m) : 0.f;
    float s = wave_reduce_sum(ex);
    __syncthreads();
    if (lane == 0) red[w] = s;
    __syncthreads();
    s = 0.f;
    #pragma unroll
    for (int i = 0; i < 8; ++i) s += red[i];
    if (tid < 256) als[tid] = ex / s;
    __syncthreads();

    float4 al = *(const float4*)&als[lane * 4];
    #pragma unroll
    for (int cc = 0; cc < 8; ++cc) {
        int c = c0 + w * 8 + cc;
        uint2 fv = *(const uint2*)(featsb + (size_t)(c * NBATCH + b) * NTIME + lane * 4);
        float sc = bflo(fv.x) * al.x + bfhi(fv.x) * al.y +
                   bflo(fv.y) * al.z + bfhi(fv.y) * al.w;
        sc = wave_reduce_sum(sc);
        if (lane == 0) ctx_bf[(size_t)b * NCH + c] = f2bf(sc);
    }
}

// ---------------------------------------------------------------------------
// Gates GEMM via MFMA: g2[j][b] = sum_k A[b][k] * Wgb[j][k], fp32 out.
// 24 blocks x 256 (4 waves 2b x 2j); block tile 128b x 128j, BK=64.
__global__ __launch_bounds__(256) void k_gmfma(const unsigned short* __restrict__ ctx_bf,
                                               const unsigned short* __restrict__ h_bf,
                                               const unsigned short* __restrict__ Wgb,
                                               float* __restrict__ g2) {
    __shared__ unsigned short As[128 * 64];   // activations [128 b][64 k]
    __shared__ unsigned short Bs[128 * 64];   // weights     [128 j][64 k]
    const int j0 = blockIdx.x * 128;
    const unsigned short* A = (j0 < 1536) ? ctx_bf : h_bf;
    const int tid = threadIdx.x;
    const int lane = tid & 63, wid = tid >> 6;
    const int wb = wid & 1, wj = wid >> 1;
    f32x4 acc[4][4];
    #pragma unroll
    for (int i = 0; i < 4; ++i)
        #pragma unroll
        for (int j = 0; j < 4; ++j) acc[i][j] = (f32x4)0.f;

    for (int k0 = 0; k0 < 512; k0 += 64) {
        #pragma unroll
        for (int i = 0; i < 4; ++i) {
            int cid = tid + i * 256;               // 1024: 128 rows x 8 chunks
            int row = cid >> 3, ch = cid & 7;
            uint4 va = *(const uint4*)(A + (size_t)row * 512 + k0 + ch * 8);
            *(uint4*)(As + row * 64 + ((ch ^ (row & 7)) << 3)) = va;
            uint4 vb = *(const uint4*)(Wgb + (size_t)(j0 + row) * 512 + k0 + ch * 8);
            *(uint4*)(Bs + row * 64 + ((ch ^ (row & 7)) << 3)) = vb;
        }
        __syncthreads();
        #pragma unroll
        for (int ks = 0; ks < 2; ++ks) {
            short8v a[4], b[4];
            #pragma unroll
            for (int f = 0; f < 4; ++f) {
                int rowa = wb * 64 + f * 16 + (lane & 15);
                int rowb = wj * 64 + f * 16 + (lane & 15);
                int ch = ks * 4 + (lane >> 4);
                a[f] = *(const short8v*)(As + rowa * 64 + ((ch ^ (rowa & 7)) << 3));
                b[f] = *(const short8v*)(Bs + rowb * 64 + ((ch ^ (rowb & 7)) << 3));
            }
            #pragma unroll
            for (int bf = 0; bf < 4; ++bf)
                #pragma unroll
                for (int jf = 0; jf < 4; ++jf)
                    acc[bf][jf] = __builtin_amdgcn_mfma_f32_16x16x32_bf16(
                        a[bf], b[jf], acc[bf][jf], 0, 0, 0);
        }
        __syncthreads();
    }
    #pragma unroll
    for (int bf = 0; bf < 4; ++bf) {
        int b = wb * 64 + bf * 16 + (lane >> 4) * 4;
        #pragma unroll
        for (int jf = 0; jf < 4; ++jf) {
            int j = j0 + wj * 64 + jf * 16 + (lane & 15);
            *(f32x4*)(g2 + (size_t)j * NBATCH + b) = acc[bf][jf];
        }
    }
}

// ---------------------------------------------------------------------------
// Fused GRU-combine + next hp (WTb bf16). Writes h_bf for next step's gates.
__global__ __launch_bounds__(1024) void k_comb_hp(const float* __restrict__ g2,
                                                  const float* __restrict__ hprev,
                                                  float* __restrict__ hidn,
                                                  unsigned short* __restrict__ h_bf,
                                                  const float* __restrict__ bih,
                                                  const float* __restrict__ bhh,
                                                  const unsigned short* __restrict__ WTb,
                                                  const float* __restrict__ bh2h,
                                                  float* __restrict__ hp) {
    __shared__ float h_s[4 * 512];
    __shared__ float scr2[16 * 4 * 16 * 4];
    const int blk = blockIdx.x;
    const int b0 = (blk >> 3) * 4;
    const int jbase = (blk & 7) * 64;
    const int tid = threadIdx.x;
    #pragma unroll
    for (int rep = 0; rep < 2; ++rep) {
        int idx = tid + rep * 1024;
        int bi = idx & 3, kk = idx >> 2;
        int b = b0 + bi;
        float ir  = g2[(size_t)(0 * 512 + kk) * NBATCH + b] + bih[kk];
        float iz  = g2[(size_t)(1 * 512 + kk) * NBATCH + b] + bih[512 + kk];
        float in_ = g2[(size_t)(2 * 512 + kk) * NBATCH + b] + bih[1024 + kk];
        float hr  = g2[(size_t)(3 * 512 + kk) * NBATCH + b] + bhh[kk];
        float hz  = g2[(size_t)(4 * 512 + kk) * NBATCH + b] + bhh[512 + kk];
        float hn  = g2[(size_t)(5 * 512 + kk) * NBATCH + b] + bhh[1024 + kk];
        float r = fast_sigmoid(ir + hr);
        float z = fast_sigmoid(iz + hz);
        float ng = fast_tanh(in_ + r * hn);
        float hv = hprev[(size_t)b * NH + kk];
        float hnew = (1.f - z) * ng + z * hv;
        h_s[bi * 512 + kk] = hnew;
        if ((blk & 7) == 0) {
            hidn[(size_t)b * NH + kk] = hnew;
            h_bf[(size_t)b * NH + kk] = f2bf(hnew);
        }
    }
    __syncthreads();
    {
        const int jq = tid & 15, bi = (tid >> 4) & 3, kq = tid >> 6;
        const int j = jbase + jq * 4;
        float4 acc = make_float4(0.f, 0.f, 0.f, 0.f);
        #pragma unroll 8
        for (int kk = 0; kk < 32; ++kk) {
            int k = kq * 32 + kk;
            uint2 wq = *(const uint2*)(WTb + (size_t)k * NH + j);
            float hv = h_s[bi * 512 + k];
            acc.x += hv * bflo(wq.x); acc.y += hv * bfhi(wq.x);
            acc.z += hv * bflo(wq.y); acc.w += hv * bfhi(wq.y);
        }
        *(float4*)&scr2[((kq * 4 + bi) * 16 + jq) * 4] = acc;
    }
    __syncthreads();
    if (tid < 64) {
        const int bi = tid >> 4, jq = tid & 15;
        float4 sum = make_float4(0.f, 0.f, 0.f, 0.f);
        #pragma unroll
        for (int kq = 0; kq < 16; ++kq) {
            float4 p = *(const float4*)&scr2[((kq * 4 + bi) * 16 + jq) * 4];
            sum.x += p.x; sum.y += p.y; sum.z += p.z; sum.w += p.w;
        }
        int j = jbase + jq * 4;
        float4 bb = *(const float4*)(bh2h + j);
        sum.x += bb.x; sum.y += bb.y; sum.z += bb.z; sum.w += bb.w;
        *(float4*)(hp + (size_t)(b0 + bi) * NH + j) = sum;
    }
}

// ---------------------------------------------------------------------------
__global__ __launch_bounds__(256) void k_gen(const float* __restrict__ hid,
                                             const float* __restrict__ Wgen,
                                             const float* __restrict__ bgen,
                                             float* __restrict__ out) {
    __shared__ float As[32][36];
    __shared__ float Bs[32][97];
    const int m0 = blockIdx.x * 32;
    const int tid = threadIdx.x;
    const int tx = tid & 31, ty = tid >> 5;
    float acc[4][3] = {};
    for (int k0 = 0; k0 < 512; k0 += 32) {
        {
            int mm = tid >> 3, kq = (tid & 7) << 2;
            int m = m0 + mm, s = m & 31, b = m >> 5;
            float4 v = *(const float4*)(hid + (size_t)(s + 1) * 65536 + b * 512 + k0 + kq);
            *(float4*)(&As[mm][kq]) = v;
        }
        #pragma unroll
        for (int i = 0; i < 3; ++i) {
            int f4 = tid + i * 256;
            int nn = f4 >> 3, kq = (f4 & 7) << 2;
            float4 v = *(const float4*)(Wgen + (size_t)nn * 512 + k0 + kq);
            Bs[kq + 0][nn] = v.x; Bs[kq + 1][nn] = v.y;
            Bs[kq + 2][nn] = v.z; Bs[kq + 3][nn] = v.w;
        }
        __syncthreads();
        #pragma unroll
        for (int kk = 0; kk < 32; ++kk) {
            float bv[3];
            #pragma unroll
            for (int j = 0; j < 3; ++j) bv[j] = Bs[kk][tx * 3 + j];
            #pragma unroll
            for (int i = 0; i < 4; ++i) {
                float a = As[ty * 4 + i][kk];
                #pragma unroll
                for (int j = 0; j < 3; ++j) acc[i][j] += a * bv[j];
            }
        }
        __syncthreads();
    }
    #pragma unroll
    for (int i = 0; i < 4; ++i)
        #pragma unroll
        for (int j = 0; j < 3; ++j)
            out[(size_t)(m0 + ty * 4 + i) * NOUT + tx * 3 + j] = acc[i][j] + bgen[tx * 3 + j];
}

// ---------------------------------------------------------------------------
extern "C" void kernel_launch(void* const* d_in, const int* in_sizes, int n_in,
                              void* d_out, int out_size, void* d_ws, size_t ws_size,
                              hipStream_t stream) {
    const float* feats  = (const float*)d_in[0];
    const float* Wi2h   = (const float*)d_in[2];
    const float* Wh2h   = (const float*)d_in[3];
    const float* bh2h   = (const float*)d_in[4];
    const float* Wscore = (const float*)d_in[5];
    const float* Wih    = (const float*)d_in[6];
    const float* Whh    = (const float*)d_in[7];
    const float* bih    = (const float*)d_in[8];
    const float* bhh    = (const float*)d_in[9];
    const float* Wgen   = (const float*)d_in[10];
    const float* bgen   = (const float*)d_in[11];
    float* out = (float*)d_out;

    // ws layout (float-slot offsets), ~80.5 MB total:
    float* ws  = (float*)d_ws;
    unsigned short* fp_bf  = (unsigned short*)ws;                    // 16,777,216 bf16
    float*          hid    = ws + 8388608;                           // 2,162,688 f32
    float*          hpctx  = hid + 2162688;                          // 65,536 f32 (hp only)
    unsigned short* ctx_bf = (unsigned short*)(hpctx + 65536);       // 65,536 bf16
    unsigned short* h_bf   = (unsigned short*)(hpctx + 65536 + 32768);   // 65,536 bf16
    unsigned short* WTb    = (unsigned short*)(hpctx + 65536 + 65536);   // 262,144 bf16
    unsigned short* Wgb    = (unsigned short*)(hpctx + 65536 + 65536 + 131072); // 1,572,864 bf16
    unsigned short* Wb     = (unsigned short*)(hpctx + 65536 + 65536 + 131072 + 786432); // 262,144 bf16
    unsigned short* Fb     = (unsigned short*)(hpctx + 65536 + 65536 + 131072 + 786432 + 131072); // 16,777,216 bf16
    unsigned short* featsb = Fb;    // reuses Fb space after k_fp_mfma

    float* e  = out;                // aliases g2 head; disjoint lifetimes
    float* g2 = out;                // 6*512*128 = 393216 = out_size

    hipMemsetAsync(hid, 0, 65536 * sizeof(float), stream);       // h0 = 0
    hipMemsetAsync(h_bf, 0, 65536 * sizeof(unsigned short), stream); // h0_bf = 0
    k_wt<<<256, 256, 0, stream>>>(Wh2h, WTb);
    k_w2bf<<<64, 256, 0, stream>>>(Wi2h, Wb);
    k_wg2bf<<<384, 256, 0, stream>>>(Wih, Whh, Wgb);
    k_feats2bf<<<4096, 256, 0, stream>>>(feats, Fb);
    k_fp_mfma<<<512, 256, 0, stream>>>(Wb, Fb, fp_bf);
    k_fcopy<<<4096, 1024, 0, stream>>>(feats, featsb);           // after mfma: Fb dead
    k_hp0<<<64, 1024, 0, stream>>>(bh2h, hpctx);

    for (int s = 0; s < NSTEPS; ++s) {
        const float* h = hid + (size_t)s * 65536;
        float* hn      = hid + (size_t)(s + 1) * 65536;
        k_e<<<1024, 512, 0, stream>>>(fp_bf, hpctx, Wscore, e);
        k_ctx2<<<1024, 512, 0, stream>>>(e, featsb, ctx_bf);
        k_gmfma<<<24, 256, 0, stream>>>(ctx_bf, h_bf, Wgb, g2);
        k_comb_hp<<<256, 1024, 0, stream>>>(g2, h, hn, h_bf, bih, bhh, WTb, bh2h, hpctx);
    }
    k_gen<<<128, 256, 0, stream>>>(hid, Wgen, bgen, out);
}